// Round 8
// baseline (6571.889 us; speedup 1.0000x reference)
//
#include <hip/hip_runtime.h>

#define LSEQ 512
#define BATCH 256
#define KDIM 256
#define STATE 128

using f32x4  = __attribute__((ext_vector_type(4))) float;
using short8 = __attribute__((ext_vector_type(8))) short;
using i32x4  = __attribute__((ext_vector_type(4))) int;

__device__ __forceinline__ float bf2f(unsigned short u){
  return __uint_as_float(((unsigned int)u) << 16);
}
__device__ __forceinline__ unsigned short f2bf(float f){
  unsigned int u = __float_as_uint(f);
  u += 0x7FFFu + ((u >> 16) & 1u);   // RNE
  return (unsigned short)(u >> 16);
}
__device__ __forceinline__ float fast_tanh(float x){
  float ax = fabsf(x);
  float e  = __expf(2.0f * ax);
  float t  = 1.0f - 2.0f / (e + 1.0f);
  return copysignf(t, x);
}
__device__ __forceinline__ float fast_sig(float x){
  return 1.0f / (1.0f + __expf(-x));
}
__device__ __forceinline__ f32x4 mfma16(short8 a, short8 b, f32x4 c){
  return __builtin_amdgcn_mfma_f32_16x16x32_bf16(a, b, c, 0, 0, 0);
}
__device__ __forceinline__ i32x4 mfma_i8(i32x4 a, i32x4 b, i32x4 c){
  return __builtin_amdgcn_mfma_i32_16x16x64_i8(a, b, c, 0, 0, 0);
}

__device__ __forceinline__ int swz128 (int b){ return b ^ ((((b >> 7) & 7) << 4)); }
__device__ __forceinline__ int swz512 (int b){ return b ^ ((((b >> 9) & 7) << 4)); }

// ---------------- weight convert: f32 src[rowoff+k][coloff+n] -> bf16 dst[n*K+k] ----------------
struct WDesc { const float* src; unsigned short* dst; int K, N, ld, rowoff, coloff; };
struct WDescs { WDesc d[10]; };

__global__ __launch_bounds__(256,4) void convert_weights(WDescs ds){
  WDesc w = ds.d[blockIdx.y];
  int total = w.K * w.N;
  int idx = blockIdx.x * 256 + threadIdx.x;
  if (idx < total){
    int n = idx / w.K;
    int k = idx - n * w.K;
    w.dst[idx] = f2bf(w.src[(size_t)(w.rowoff + k) * w.ld + w.coloff + n]);
  }
}

// ---------------- weight convert: f32 -> int8 transposed [n][k], static scale ----------------
struct QDesc { const float* src; signed char* dst; int K, N, ld; float inv_s; };
struct QDescs { QDesc d[7]; };

__global__ __launch_bounds__(256,4) void convert_q8(QDescs ds){
  QDesc w = ds.d[blockIdx.y];
  int idx = blockIdx.x * 256 + threadIdx.x;
  if (idx < w.K * w.N){
    int n = idx / w.K;
    int k = idx - n * w.K;
    float v = w.src[(size_t)k * w.ld + n] * w.inv_s;
    v = fminf(fmaxf(rintf(v), -127.0f), 127.0f);
    w.dst[idx] = (signed char)(int)v;
  }
}

// ---------------- multi-descriptor bf16 MFMA GEMM ----------------
struct GArg {
  const void* A; const unsigned short* Bt; const float* bias; const float* bias2;
  unsigned short* C; int lda, ldc, coff, K, act, a_f32;
};
struct GArgs { GArg g[4]; };

__global__ __launch_bounds__(256,2) void gemm_multi(GArgs args){
  GArg ga = args.g[blockIdx.z];
  __shared__ __align__(16) unsigned short lsA[128*64];
  __shared__ __align__(16) unsigned short lsB[128*64];
  const int tid  = threadIdx.x;
  const int wave = tid >> 6, lane = tid & 63;
  const int col_l = lane & 15, rgrp = lane >> 4;
  const int m0 = blockIdx.x * 128, n0 = blockIdx.y * 128;
  const int wm = (wave >> 1) * 64, wn = (wave & 1) * 64;

  f32x4 acc[4][4];
  const f32x4 z4 = {0.f,0.f,0.f,0.f};
  #pragma unroll
  for (int i=0;i<4;i++){ acc[i][0]=z4; acc[i][1]=z4; acc[i][2]=z4; acc[i][3]=z4; }

  const int srow = tid >> 1;
  const int sbe  = (tid & 1) * 32;

  for (int k0 = 0; k0 < ga.K; k0 += 64){
    uint4 av[4], bv[4];
    if (ga.a_f32){
      const float* Ap = (const float*)ga.A + (size_t)(m0 + srow) * ga.lda + k0 + sbe;
      uint4 fv[8];
      #pragma unroll
      for (int i=0;i<8;i++) fv[i] = *(const uint4*)((const char*)Ap + i*16);
      #pragma unroll
      for (int i=0;i<4;i++){
        const float* f = (const float*)&fv[i*2];
        uint4 o;
        o.x = (unsigned)f2bf(f[0]) | ((unsigned)f2bf(f[1]) << 16);
        o.y = (unsigned)f2bf(f[2]) | ((unsigned)f2bf(f[3]) << 16);
        o.z = (unsigned)f2bf(f[4]) | ((unsigned)f2bf(f[5]) << 16);
        o.w = (unsigned)f2bf(f[6]) | ((unsigned)f2bf(f[7]) << 16);
        av[i] = o;
      }
    } else {
      const unsigned short* Ap = (const unsigned short*)ga.A + (size_t)(m0 + srow) * ga.lda + k0 + sbe;
      #pragma unroll
      for (int i=0;i<4;i++) av[i] = *(const uint4*)((const char*)Ap + i*16);
    }
    const unsigned short* Bp = ga.Bt + (size_t)(n0 + srow) * ga.K + k0 + sbe;
    #pragma unroll
    for (int i=0;i<4;i++) bv[i] = *(const uint4*)((const char*)Bp + i*16);

    __syncthreads();
    #pragma unroll
    for (int i=0;i<4;i++){
      *(uint4*)((char*)lsA + swz128(srow*128 + sbe*2 + i*16)) = av[i];
      *(uint4*)((char*)lsB + swz128(srow*128 + sbe*2 + i*16)) = bv[i];
    }
    __syncthreads();
    #pragma unroll
    for (int kk=0; kk<2; kk++){
      short8 af[4], bfr[4];
      #pragma unroll
      for (int mt=0; mt<4; mt++)
        af[mt] = *(const short8*)((const char*)lsA + swz128((wm + mt*16 + col_l)*128 + kk*64 + rgrp*16));
      #pragma unroll
      for (int nt=0; nt<4; nt++)
        bfr[nt] = *(const short8*)((const char*)lsB + swz128((wn + nt*16 + col_l)*128 + kk*64 + rgrp*16));
      #pragma unroll
      for (int mt=0; mt<4; mt++)
        #pragma unroll
        for (int nt=0; nt<4; nt++)
          acc[mt][nt] = mfma16(af[mt], bfr[nt], acc[mt][nt]);
    }
  }
  #pragma unroll
  for (int nt=0; nt<4; nt++){
    int col = n0 + wn + nt*16 + col_l;
    const float* bsrc = (col < 512) ? ga.bias : ga.bias2;
    float bb = bsrc ? bsrc[col & 511] : 0.0f;
    #pragma unroll
    for (int mt=0; mt<4; mt++){
      #pragma unroll
      for (int r=0; r<4; r++){
        int row = m0 + wm + mt*16 + rgrp*4 + r;
        float v = acc[mt][nt][r] + bb;
        if (ga.act == 1) v = fast_tanh(v);
        ga.C[(size_t)row * ga.ldc + ga.coff + col] = f2bf(v);
      }
    }
  }
}

// ---------------- phase B: tanh-RNN chunk, W_hh held in VGPRs ----------------
__global__ __launch_bounds__(256,1) void rnn_chunk(
    const unsigned short* __restrict__ rnn_in,
    const unsigned short* __restrict__ Whh_t,
    const float* __restrict__ b_hh,
    unsigned short* __restrict__ cat_d,
    float* __restrict__ dn_out,
    unsigned short* __restrict__ d_state,
    int t0, int nsteps)
{
  __shared__ __align__(16) unsigned short dls[16*256];
  const int tid = threadIdx.x, wave = tid >> 6, lane = tid & 63;
  const int col_l = lane & 15, rgrp = lane >> 4;
  const int brow0 = blockIdx.x * 16;
  const int ncol = wave * 64;

  short8 bfr[4][8];
  #pragma unroll
  for (int nt=0; nt<4; nt++){
    const unsigned short* bp = Whh_t + (size_t)(ncol + nt*16 + col_l) * 256;
    #pragma unroll
    for (int kk=0; kk<8; kk++)
      bfr[nt][kk] = *(const short8*)(bp + kk*32 + rgrp*8);
  }
  float bias[4];
  #pragma unroll
  for (int nt=0; nt<4; nt++) bias[nt] = b_hh[ncol + nt*16 + col_l];

  if (t0 == 0){
    for (int i = tid; i < 16*256; i += 256){
      int row = i >> 8, col = i & 255;
      *(unsigned short*)((char*)dls + swz512(row*512 + col*2)) = 0;
    }
  } else {
    const unsigned short* ds = d_state + (size_t)brow0 * 256;
    for (int i = tid; i < 16*256; i += 256){
      int row = i >> 8, col = i & 255;
      *(unsigned short*)((char*)dls + swz512(row*512 + col*2)) = ds[row*256 + col];
    }
  }
  __syncthreads();

  for (int tl=0; tl<nsteps; tl++){
    unsigned short rv[4][4];
    const unsigned short* rp = rnn_in + (size_t)(tl*BATCH + brow0) * 256;
    #pragma unroll
    for (int nt=0; nt<4; nt++)
      #pragma unroll
      for (int r=0; r<4; r++)
        rv[nt][r] = rp[(size_t)(rgrp*4 + r)*256 + ncol + nt*16 + col_l];

    f32x4 acc[4];
    const f32x4 z4 = {0.f,0.f,0.f,0.f};
    acc[0]=z4; acc[1]=z4; acc[2]=z4; acc[3]=z4;
    #pragma unroll
    for (int kk=0; kk<8; kk++){
      short8 af = *(const short8*)((const char*)dls + swz512((lane & 15)*512 + kk*64 + rgrp*16));
      #pragma unroll
      for (int nt=0; nt<4; nt++)
        acc[nt] = mfma16(af, bfr[nt][kk], acc[nt]);
    }
    __syncthreads();
    #pragma unroll
    for (int nt=0; nt<4; nt++){
      #pragma unroll
      for (int r=0; r<4; r++){
        float h = acc[nt][r] + bf2f(rv[nt][r]) + bias[nt];
        float d = fast_tanh(h);
        int row = rgrp*4 + r, col = ncol + nt*16 + col_l;
        unsigned short db = f2bf(d);
        *(unsigned short*)((char*)dls + swz512(row*512 + col*2)) = db;
        cat_d[(size_t)(tl*BATCH + brow0 + row)*512 + col] = db;
        if (t0 + tl == LSEQ-1) dn_out[(size_t)(brow0 + row)*256 + col] = d;
      }
    }
    __syncthreads();
  }
  unsigned short* dso = d_state + (size_t)brow0 * 256;
  for (int i = tid; i < 16*256; i += 256){
    int row = i >> 8, col = i & 255;
    dso[row*256 + col] = *(const unsigned short*)((const char*)dls + swz512(row*512 + col*2));
  }
}

// ---------------- phase D: SINGLE-CU z recurrence, int8 weights, no cross-CU sync ----------------
// 16 wgs x 16 batch rows; 512 threads (8 waves); ALL DBlock weights on-CU:
//   VGPR: GEMM1 W1[4][512n][128k] i8 (128 regs) + mu_q[128n][512k] i8 (32 regs)
//   LDS (dynamic 150016B): mu_p + ls_p (128KB, XOR-swizzled) + t (16x1040) + z (16x144)
// Static per-matrix scales (Glorot sigma known): 5-sigma -> 127.
__global__ __launch_bounds__(512, 2) void zrec_i8(
    const unsigned short* __restrict__ preP, const unsigned short* __restrict__ preQ, // [ns*B,1024] bf16
    const signed char* __restrict__ W1q,   // [4 mats][512 n][128 k]: f1p,f2p,f1q,f2q
    const signed char* __restrict__ W2q,   // [3 mats][128 n][512 k]: mu_p, ls_p, mu_q
    const float* __restrict__ pmub, const float* __restrict__ plsb, const float* __restrict__ qmub,
    const float* __restrict__ eps,
    float* __restrict__ out_mu, float* __restrict__ out_ls, float* __restrict__ out_zn,
    signed char* __restrict__ z_state,     // [B][128] i8 persistent
    int t0, int nsteps)
{
  extern __shared__ __align__(16) char dyn[];
  char* ls_w = dyn;                        // 131072: [mu_p | ls_p][128 n][512 k] swizzled
  char* ls_t = dyn + 131072;               // 16 x 1040 (cols: t_p 0-511, t_q 512-1023, pad)
  char* ls_z = dyn + 131072 + 16640;       // 16 x 144

  const int tid = threadIdx.x, wave = tid >> 6, lane = tid & 63;
  const int col_l = lane & 15, kg = lane >> 4;
  const int brow0 = blockIdx.x * 16;
  const int d  = wave >> 2;                // dblock: 0=posterior, 1=prior
  const int cb = (wave & 3) * 128;         // GEMM1 col base (within 512 hid)
  const int hc = wave * 16 + col_l;        // GEMM2 head column (0..127)

  const float DS1 = (10.0f/127.0f) * (5.0f/(127.0f*19.59591794f)); // z-scale * W1-scale
  const float DS2 = (1.0f/127.0f)  * (5.0f/(127.0f*22.62741700f)); // t-scale * W2-scale

  // GEMM1 weights -> VGPR (this wave: both f1 and f2 of dblock d, cols cb..cb+127)
  i32x4 w1f[2][8][2];
  #pragma unroll
  for (int f=0; f<2; f++){
    int m = d*2 + f;
    #pragma unroll
    for (int j=0; j<8; j++){
      int n = cb + j*16 + col_l;
      const signed char* base = W1q + ((size_t)(m*512 + n) << 7) + kg*16;
      w1f[f][j][0] = *(const i32x4*)(base);
      w1f[f][j][1] = *(const i32x4*)(base + 64);
    }
  }
  // mu_q weights -> VGPR (this wave's 16 head cols)
  i32x4 wq[8];
  #pragma unroll
  for (int ks=0; ks<8; ks++)
    wq[ks] = *(const i32x4*)(W2q + ((size_t)(2*128 + hc) << 9) + ks*64 + kg*16);

  const float bp = pmub[hc], bl = plsb[hc], bq = qmub[hc];

  // fill LDS weights (mu_p, ls_p) with XOR swizzle on k
  for (int i = tid; i < 8192; i += 512){
    int m = i >> 12, rest = i & 4095, n = rest >> 5, k16 = (rest & 31) << 4;
    i32x4 v = *(const i32x4*)(W2q + ((size_t)(m*128 + n) << 9) + k16);
    *(i32x4*)(ls_w + (m << 16) + (n << 9) + (k16 ^ ((n & 7) << 4))) = v;
  }
  // init z
  if (t0 == 0){
    for (int i = tid; i < 2304; i += 512) ls_z[i] = 0;
  } else {
    for (int i = tid; i < 2048; i += 512){
      int row = i >> 7, col = i & 127;
      ls_z[row*144 + col] = z_state[(size_t)(brow0 + row)*128 + col];
    }
  }
  __syncthreads();

  const unsigned short* pre = d ? preQ : preP;

  for (int tl = 0; tl < nsteps; ++tl){
    // GEMM1 A-frags (z, i8)
    i32x4 zf0 = *(const i32x4*)(ls_z + col_l*144 + kg*16);
    i32x4 zf1 = *(const i32x4*)(ls_z + col_l*144 + 64 + kg*16);
    const unsigned short* pb = pre + ((size_t)(tl*BATCH) + brow0 + kg*4) * 1024;

    #pragma unroll
    for (int q = 0; q < 4; q++){
      int c0 = cb + q*32;
      unsigned short pv[2][2][4];
      #pragma unroll
      for (int f=0; f<2; f++)
        #pragma unroll
        for (int nt=0; nt<2; nt++)
          #pragma unroll
          for (int r=0; r<4; r++)
            pv[f][nt][r] = pb[(size_t)r*1024 + f*512 + c0 + nt*16 + col_l];

      i32x4 acc[2][2];
      const i32x4 zz = {0,0,0,0};
      acc[0][0]=zz; acc[0][1]=zz; acc[1][0]=zz; acc[1][1]=zz;
      #pragma unroll
      for (int f=0; f<2; f++)
        #pragma unroll
        for (int nt=0; nt<2; nt++){
          acc[f][nt] = mfma_i8(zf0, w1f[f][q*2+nt][0], acc[f][nt]);
          acc[f][nt] = mfma_i8(zf1, w1f[f][q*2+nt][1], acc[f][nt]);
        }
      #pragma unroll
      for (int nt=0; nt<2; nt++)
        #pragma unroll
        for (int r=0; r<4; r++){
          float h1 = (float)acc[0][nt][r] * DS1 + bf2f(pv[0][nt][r]);
          float h2 = (float)acc[1][nt][r] * DS1 + bf2f(pv[1][nt][r]);
          float tv = fast_tanh(h1) * fast_sig(h2);
          float tq = fminf(fmaxf(rintf(tv * 127.0f), -127.0f), 127.0f);
          ls_t[(kg*4 + r)*1040 + d*512 + c0 + nt*16 + col_l] = (signed char)(int)tq;
        }
    }
    __syncthreads();    // t visible

    // eps for this thread's outputs
    size_t growr = (size_t)(t0 + tl)*BATCH + brow0 + kg*4;
    float er[4];
    #pragma unroll
    for (int r=0; r<4; r++) er[r] = eps[(growr + r)*STATE + hc];

    // GEMM2: heads (K=512), A from LDS t, B: mu_p/ls_p LDS, mu_q VGPR
    i32x4 amp = {0,0,0,0}, als = {0,0,0,0}, amq = {0,0,0,0};
    #pragma unroll
    for (int ks=0; ks<8; ks++){
      i32x4 Ap = *(const i32x4*)(ls_t + col_l*1040 + ks*64 + kg*16);
      i32x4 Aq = *(const i32x4*)(ls_t + col_l*1040 + 512 + ks*64 + kg*16);
      int ko = (ks*64 + kg*16) ^ ((hc & 7) << 4);
      i32x4 Bp = *(const i32x4*)(ls_w + (hc << 9) + ko);
      i32x4 Bl = *(const i32x4*)(ls_w + 65536 + (hc << 9) + ko);
      amp = mfma_i8(Ap, Bp, amp);
      als = mfma_i8(Ap, Bl, als);
      amq = mfma_i8(Aq, wq[ks], amq);
    }
    // epilogue: mu, ls, z
    #pragma unroll
    for (int r=0; r<4; r++){
      float mu = ((float)amq[r] * DS2 + bq) + ((float)amp[r] * DS2 + bp);
      float ls = (float)als[r] * DS2 + bl;
      float z  = mu + __expf(0.5f * ls) * er[r];
      int row = kg*4 + r;
      out_mu[(growr + r)*STATE + hc] = mu;
      out_ls[(growr + r)*STATE + hc] = ls;
      if (t0 + tl == LSEQ-1) out_zn[(size_t)(brow0 + row)*STATE + hc] = z;
      float zq = fminf(fmaxf(rintf(z * 12.7f), -127.0f), 127.0f);
      ls_z[row*144 + hc] = (signed char)(int)zq;
    }
    __syncthreads();    // z visible; t reusable
  }

  // persist z state (i8)
  for (int i = tid; i < 2048; i += 512){
    int row = i >> 7, col = i & 127;
    z_state[(size_t)(brow0 + row)*128 + col] = ls_z[row*144 + col];
  }
}

// ---------------- host launcher ----------------
extern "C" void kernel_launch(void* const* d_in, const int* in_sizes, int n_in,
                              void* d_out, int out_size, void* d_ws, size_t ws_size,
                              hipStream_t stream)
{
  const float* ext = (const float*)d_in[0];
  const float* obs = (const float*)d_in[1];
  const float* eps = (const float*)d_in[2];
  const float* Wu  = (const float*)d_in[3];
  const float* bu  = (const float*)d_in[4];
  const float* Wx  = (const float*)d_in[5];
  const float* bx  = (const float*)d_in[6];
  const float* W_ih= (const float*)d_in[7];
  const float* b_ih= (const float*)d_in[8];
  const float* W_hh= (const float*)d_in[9];
  const float* b_hh= (const float*)d_in[10];
  const float* Wa1 = (const float*)d_in[11];
  const float* ba1 = (const float*)d_in[12];
  const float* Wa2 = (const float*)d_in[13];
  const float* ba2 = (const float*)d_in[14];
  const float* pf1W= (const float*)d_in[15]; const float* pf1b = (const float*)d_in[16];
  const float* pf2W= (const float*)d_in[17]; const float* pf2b = (const float*)d_in[18];
  const float* pmuW= (const float*)d_in[19]; const float* pmub = (const float*)d_in[20];
  const float* plsW= (const float*)d_in[21]; const float* plsb = (const float*)d_in[22];
  const float* qf1W= (const float*)d_in[23]; const float* qf1b = (const float*)d_in[24];
  const float* qf2W= (const float*)d_in[25]; const float* qf2b = (const float*)d_in[26];
  const float* qmuW= (const float*)d_in[27]; const float* qmub = (const float*)d_in[28];

  int NC = 0;
  const int cands[7] = {1,2,4,8,16,32,64};
  size_t rows = 0;
  for (int ci=0; ci<7; ci++){
    size_t r = (size_t)(LSEQ/cands[ci])*BATCH;
    size_t elems = 1600000 + r*3072;
    if (elems * 2 <= ws_size){ NC = cands[ci]; rows = r; break; }
  }
  if (!NC) return;
  const int nsteps = LSEQ/NC;
  const int gx = (int)(rows/128);

  unsigned short* ws = (unsigned short*)d_ws;
  size_t off = 0;
  auto alloc = [&](size_t elems){
    unsigned short* p = ws + off;
    off += (elems + 127) & ~(size_t)127;
    return p;
  };

  unsigned short* Wu_t  = alloc(64*256);
  unsigned short* Wx_t  = alloc(64*256);
  unsigned short* Wih_t = alloc(256*256);
  unsigned short* Whh_t = alloc(256*256);
  unsigned short* Wa1_t = alloc(512*256);
  unsigned short* Wa2_t = alloc(256*256);
  unsigned short* fAp   = alloc(1024*256);     // [f1(512) | f2(512)] x [256 k]
  unsigned short* fAq   = alloc(1024*256);
  signed char*    W1q   = (signed char*)alloc(131072);  // 262144 B
  signed char*    W2q   = (signed char*)alloc(98304);   // 196608 B
  unsigned short* d_state = alloc(256*256);
  signed char*    z_state = (signed char*)alloc(16384); // 32768 B
  unsigned short* bufA  = alloc(rows*256);
  unsigned short* bufB  = alloc(rows*256);
  unsigned short* bufC  = alloc(rows*512);
  unsigned short* preP  = alloc(rows*1024);
  unsigned short* preQ  = alloc(rows*1024);
  if (off * sizeof(unsigned short) > ws_size) return;

  float* out_mu = (float*)d_out;
  float* out_ls = out_mu + (size_t)LSEQ*BATCH*STATE;
  float* out_dn = out_ls + (size_t)LSEQ*BATCH*STATE;
  float* out_zn = out_dn + (size_t)BATCH*KDIM;

  WDescs wd;
  int wi = 0;
  auto add = [&](const float* s, unsigned short* dst, int Kk, int Nn, int ld, int ro, int co){
    wd.d[wi].src = s; wd.d[wi].dst = dst; wd.d[wi].K = Kk; wd.d[wi].N = Nn;
    wd.d[wi].ld = ld; wd.d[wi].rowoff = ro; wd.d[wi].coloff = co; wi++;
  };
  add(Wu,   Wu_t,  64, 256, 256, 0, 0);
  add(Wx,   Wx_t,  64, 256, 256, 0, 0);
  add(W_ih, Wih_t, 256, 256, 256, 0, 0);
  add(W_hh, Whh_t, 256, 256, 256, 0, 0);
  add(Wa1,  Wa1_t, 512, 256, 256, 0, 0);
  add(Wa2,  Wa2_t, 256, 256, 256, 0, 0);
  add(pf1W, fAp,            256, 512, 512, 128, 0);
  add(pf2W, fAp + 512*256,  256, 512, 512, 128, 0);
  add(qf1W, fAq,            256, 512, 512, 128, 0);
  add(qf2W, fAq + 512*256,  256, 512, 512, 128, 0);

  const float INV1 = 127.0f * 19.59591794f / 5.0f;  // 1/s for fan_in 384 mats
  const float INV2 = 127.0f * 22.62741700f / 5.0f;  // 1/s for fan_in 512 mats
  QDescs qd;
  auto addq = [&](int i, const float* s, signed char* dst, int Kk, int Nn, int ld, float is){
    qd.d[i].src = s; qd.d[i].dst = dst; qd.d[i].K = Kk; qd.d[i].N = Nn;
    qd.d[i].ld = ld; qd.d[i].inv_s = is;
  };
  addq(0, pf1W, W1q + 0*65536, 128, 512, 512, INV1);
  addq(1, pf2W, W1q + 1*65536, 128, 512, 512, INV1);
  addq(2, qf1W, W1q + 2*65536, 128, 512, 512, INV1);
  addq(3, qf2W, W1q + 3*65536, 128, 512, 512, INV1);
  addq(4, pmuW, W2q + 0*65536, 512, 128, 128, INV2);
  addq(5, plsW, W2q + 1*65536, 512, 128, 128, INV2);
  addq(6, qmuW, W2q + 2*65536, 512, 128, 128, INV2);

  convert_weights<<<dim3(512,10), 256, 0, stream>>>(wd);
  convert_q8<<<dim3(256,7), 256, 0, stream>>>(qd);

  hipFuncSetAttribute((const void*)zrec_i8,
                      hipFuncAttributeMaxDynamicSharedMemorySize, 150016);

  for (int c=0; c<NC; ++c){
    const int t0 = c * nsteps;
    const size_t row0 = (size_t)t0 * BATCH;

    GArgs e{};
    e.g[0] = GArg{ext + row0*64, Wu_t, bu, bu, bufA, 64, 256, 0,   64, 1, 1};
    e.g[1] = GArg{obs + row0*64, Wx_t, bx, bx, bufC, 64, 512, 256, 64, 1, 1};
    gemm_multi<<<dim3(gx,2,2), 256, 0, stream>>>(e);

    GArgs rn{};
    rn.g[0] = GArg{bufA, Wih_t, b_ih, b_ih, bufB, 256, 256, 0, 256, 0, 0};
    gemm_multi<<<dim3(gx,2,1), 256, 0, stream>>>(rn);

    rnn_chunk<<<16, 256, 0, stream>>>(bufB, Whh_t, b_hh, bufC, out_dn, d_state, t0, nsteps);

    GArgs a1{};
    a1.g[0] = GArg{bufC, Wa1_t, ba1, ba1, bufA, 512, 256, 0, 512, 1, 0};
    gemm_multi<<<dim3(gx,2,1), 256, 0, stream>>>(a1);

    GArgs a2{};
    a2.g[0] = GArg{bufA, Wa2_t, ba2, ba2, bufB, 256, 256, 0, 256, 0, 0};
    gemm_multi<<<dim3(gx,2,1), 256, 0, stream>>>(a2);

    GArgs pr{};
    pr.g[0] = GArg{bufB, fAp, pf1b, pf2b, preP, 256, 1024, 0, 256, 0, 0};
    pr.g[1] = GArg{bufC, fAq, qf1b, qf2b, preQ, 512, 1024, 0, 256, 0, 0};
    gemm_multi<<<dim3(gx,8,2), 256, 0, stream>>>(pr);

    zrec_i8<<<16, 512, 150016, stream>>>(preP, preQ, W1q, W2q,
                                         pmub, plsb, qmub, eps, out_mu, out_ls, out_zn,
                                         z_state, t0, nsteps);
  }
}

// Round 9
// 6214.901 us; speedup vs baseline: 1.0574x; 1.0574x over previous
//
#include <hip/hip_runtime.h>

#define LSEQ 512
#define BATCH 256
#define KDIM 256
#define STATE 128

using f32x4  = __attribute__((ext_vector_type(4))) float;
using short8 = __attribute__((ext_vector_type(8))) short;
using i32x4  = __attribute__((ext_vector_type(4))) int;

__device__ __forceinline__ float bf2f(unsigned short u){
  return __uint_as_float(((unsigned int)u) << 16);
}
__device__ __forceinline__ unsigned short f2bf(float f){
  unsigned int u = __float_as_uint(f);
  u += 0x7FFFu + ((u >> 16) & 1u);   // RNE
  return (unsigned short)(u >> 16);
}
__device__ __forceinline__ float fast_tanh(float x){
  float ax = fabsf(x);
  float e  = __expf(2.0f * ax);
  float t  = 1.0f - 2.0f / (e + 1.0f);
  return copysignf(t, x);
}
__device__ __forceinline__ float fast_sig(float x){
  return 1.0f / (1.0f + __expf(-x));
}
__device__ __forceinline__ f32x4 mfma16(short8 a, short8 b, f32x4 c){
  return __builtin_amdgcn_mfma_f32_16x16x32_bf16(a, b, c, 0, 0, 0);
}
__device__ __forceinline__ i32x4 mfma_i8(i32x4 a, i32x4 b, i32x4 c){
  return __builtin_amdgcn_mfma_i32_16x16x64_i8(a, b, c, 0, 0, 0);
}

__device__ __forceinline__ int swz128 (int b){ return b ^ ((((b >> 7) & 7) << 4)); }
__device__ __forceinline__ int swz512 (int b){ return b ^ ((((b >> 9) & 7) << 4)); }

// ---------------- weight convert: f32 src[rowoff+k][coloff+n] -> bf16 dst[n*K+k] ----------------
struct WDesc { const float* src; unsigned short* dst; int K, N, ld, rowoff, coloff; };
struct WDescs { WDesc d[10]; };

__global__ __launch_bounds__(256,4) void convert_weights(WDescs ds){
  WDesc w = ds.d[blockIdx.y];
  int total = w.K * w.N;
  int idx = blockIdx.x * 256 + threadIdx.x;
  if (idx < total){
    int n = idx / w.K;
    int k = idx - n * w.K;
    w.dst[idx] = f2bf(w.src[(size_t)(w.rowoff + k) * w.ld + w.coloff + n]);
  }
}

// ---------------- weight convert: f32 -> int8 transposed [n][k], static scale ----------------
struct QDesc { const float* src; signed char* dst; int K, N, ld; float inv_s; };
struct QDescs { QDesc d[7]; };

__global__ __launch_bounds__(256,4) void convert_q8(QDescs ds){
  QDesc w = ds.d[blockIdx.y];
  int idx = blockIdx.x * 256 + threadIdx.x;
  if (idx < w.K * w.N){
    int n = idx / w.K;
    int k = idx - n * w.K;
    float v = w.src[(size_t)k * w.ld + n] * w.inv_s;
    v = fminf(fmaxf(rintf(v), -127.0f), 127.0f);
    w.dst[idx] = (signed char)(int)v;
  }
}

// ---------------- multi-descriptor bf16 MFMA GEMM ----------------
struct GArg {
  const void* A; const unsigned short* Bt; const float* bias; const float* bias2;
  unsigned short* C; int lda, ldc, coff, K, act, a_f32;
};
struct GArgs { GArg g[4]; };

__global__ __launch_bounds__(256,2) void gemm_multi(GArgs args){
  GArg ga = args.g[blockIdx.z];
  __shared__ __align__(16) unsigned short lsA[128*64];
  __shared__ __align__(16) unsigned short lsB[128*64];
  const int tid  = threadIdx.x;
  const int wave = tid >> 6, lane = tid & 63;
  const int col_l = lane & 15, rgrp = lane >> 4;
  const int m0 = blockIdx.x * 128, n0 = blockIdx.y * 128;
  const int wm = (wave >> 1) * 64, wn = (wave & 1) * 64;

  f32x4 acc[4][4];
  const f32x4 z4 = {0.f,0.f,0.f,0.f};
  #pragma unroll
  for (int i=0;i<4;i++){ acc[i][0]=z4; acc[i][1]=z4; acc[i][2]=z4; acc[i][3]=z4; }

  const int srow = tid >> 1;
  const int sbe  = (tid & 1) * 32;

  for (int k0 = 0; k0 < ga.K; k0 += 64){
    uint4 av[4], bv[4];
    if (ga.a_f32){
      const float* Ap = (const float*)ga.A + (size_t)(m0 + srow) * ga.lda + k0 + sbe;
      uint4 fv[8];
      #pragma unroll
      for (int i=0;i<8;i++) fv[i] = *(const uint4*)((const char*)Ap + i*16);
      #pragma unroll
      for (int i=0;i<4;i++){
        const float* f = (const float*)&fv[i*2];
        uint4 o;
        o.x = (unsigned)f2bf(f[0]) | ((unsigned)f2bf(f[1]) << 16);
        o.y = (unsigned)f2bf(f[2]) | ((unsigned)f2bf(f[3]) << 16);
        o.z = (unsigned)f2bf(f[4]) | ((unsigned)f2bf(f[5]) << 16);
        o.w = (unsigned)f2bf(f[6]) | ((unsigned)f2bf(f[7]) << 16);
        av[i] = o;
      }
    } else {
      const unsigned short* Ap = (const unsigned short*)ga.A + (size_t)(m0 + srow) * ga.lda + k0 + sbe;
      #pragma unroll
      for (int i=0;i<4;i++) av[i] = *(const uint4*)((const char*)Ap + i*16);
    }
    const unsigned short* Bp = ga.Bt + (size_t)(n0 + srow) * ga.K + k0 + sbe;
    #pragma unroll
    for (int i=0;i<4;i++) bv[i] = *(const uint4*)((const char*)Bp + i*16);

    __syncthreads();
    #pragma unroll
    for (int i=0;i<4;i++){
      *(uint4*)((char*)lsA + swz128(srow*128 + sbe*2 + i*16)) = av[i];
      *(uint4*)((char*)lsB + swz128(srow*128 + sbe*2 + i*16)) = bv[i];
    }
    __syncthreads();
    #pragma unroll
    for (int kk=0; kk<2; kk++){
      short8 af[4], bfr[4];
      #pragma unroll
      for (int mt=0; mt<4; mt++)
        af[mt] = *(const short8*)((const char*)lsA + swz128((wm + mt*16 + col_l)*128 + kk*64 + rgrp*16));
      #pragma unroll
      for (int nt=0; nt<4; nt++)
        bfr[nt] = *(const short8*)((const char*)lsB + swz128((wn + nt*16 + col_l)*128 + kk*64 + rgrp*16));
      #pragma unroll
      for (int mt=0; mt<4; mt++)
        #pragma unroll
        for (int nt=0; nt<4; nt++)
          acc[mt][nt] = mfma16(af[mt], bfr[nt], acc[mt][nt]);
    }
  }
  #pragma unroll
  for (int nt=0; nt<4; nt++){
    int col = n0 + wn + nt*16 + col_l;
    const float* bsrc = (col < 512) ? ga.bias : ga.bias2;
    float bb = bsrc ? bsrc[col & 511] : 0.0f;
    #pragma unroll
    for (int mt=0; mt<4; mt++){
      #pragma unroll
      for (int r=0; r<4; r++){
        int row = m0 + wm + mt*16 + rgrp*4 + r;
        float v = acc[mt][nt][r] + bb;
        if (ga.act == 1) v = fast_tanh(v);
        ga.C[(size_t)row * ga.ldc + ga.coff + col] = f2bf(v);
      }
    }
  }
}

// ---------------- phase B: tanh-RNN chunk, W_hh held in VGPRs ----------------
__global__ __launch_bounds__(256,1) void rnn_chunk(
    const unsigned short* __restrict__ rnn_in,
    const unsigned short* __restrict__ Whh_t,
    const float* __restrict__ b_hh,
    unsigned short* __restrict__ cat_d,
    float* __restrict__ dn_out,
    unsigned short* __restrict__ d_state,
    int t0, int nsteps)
{
  __shared__ __align__(16) unsigned short dls[16*256];
  const int tid = threadIdx.x, wave = tid >> 6, lane = tid & 63;
  const int col_l = lane & 15, rgrp = lane >> 4;
  const int brow0 = blockIdx.x * 16;
  const int ncol = wave * 64;

  short8 bfr[4][8];
  #pragma unroll
  for (int nt=0; nt<4; nt++){
    const unsigned short* bp = Whh_t + (size_t)(ncol + nt*16 + col_l) * 256;
    #pragma unroll
    for (int kk=0; kk<8; kk++)
      bfr[nt][kk] = *(const short8*)(bp + kk*32 + rgrp*8);
  }
  float bias[4];
  #pragma unroll
  for (int nt=0; nt<4; nt++) bias[nt] = b_hh[ncol + nt*16 + col_l];

  if (t0 == 0){
    for (int i = tid; i < 16*256; i += 256){
      int row = i >> 8, col = i & 255;
      *(unsigned short*)((char*)dls + swz512(row*512 + col*2)) = 0;
    }
  } else {
    const unsigned short* ds = d_state + (size_t)brow0 * 256;
    for (int i = tid; i < 16*256; i += 256){
      int row = i >> 8, col = i & 255;
      *(unsigned short*)((char*)dls + swz512(row*512 + col*2)) = ds[row*256 + col];
    }
  }
  __syncthreads();

  for (int tl=0; tl<nsteps; tl++){
    unsigned short rv[4][4];
    const unsigned short* rp = rnn_in + (size_t)(tl*BATCH + brow0) * 256;
    #pragma unroll
    for (int nt=0; nt<4; nt++)
      #pragma unroll
      for (int r=0; r<4; r++)
        rv[nt][r] = rp[(size_t)(rgrp*4 + r)*256 + ncol + nt*16 + col_l];

    f32x4 acc[4];
    const f32x4 z4 = {0.f,0.f,0.f,0.f};
    acc[0]=z4; acc[1]=z4; acc[2]=z4; acc[3]=z4;
    #pragma unroll
    for (int kk=0; kk<8; kk++){
      short8 af = *(const short8*)((const char*)dls + swz512((lane & 15)*512 + kk*64 + rgrp*16));
      #pragma unroll
      for (int nt=0; nt<4; nt++)
        acc[nt] = mfma16(af, bfr[nt][kk], acc[nt]);
    }
    __syncthreads();
    #pragma unroll
    for (int nt=0; nt<4; nt++){
      #pragma unroll
      for (int r=0; r<4; r++){
        float h = acc[nt][r] + bf2f(rv[nt][r]) + bias[nt];
        float d = fast_tanh(h);
        int row = rgrp*4 + r, col = ncol + nt*16 + col_l;
        unsigned short db = f2bf(d);
        *(unsigned short*)((char*)dls + swz512(row*512 + col*2)) = db;
        cat_d[(size_t)(tl*BATCH + brow0 + row)*512 + col] = db;
        if (t0 + tl == LSEQ-1) dn_out[(size_t)(brow0 + row)*256 + col] = d;
      }
    }
    __syncthreads();
  }
  unsigned short* dso = d_state + (size_t)brow0 * 256;
  for (int i = tid; i < 16*256; i += 256){
    int row = i >> 8, col = i & 255;
    dso[row*256 + col] = *(const unsigned short*)((const char*)dls + swz512(row*512 + col*2));
  }
}

// ---------------- phase D: SINGLE-CU z recurrence, int8 weights, no cross-CU sync ----------------
// 16 wgs x 16 batch rows; 512 threads (8 waves), PINNED 2 waves/EU -> 256 VGPR
// budget so the 160 VGPRs of weights stay register-resident (r8's failure: the
// allocator targeted 128 and rematerialized weight loads in-loop -> 9.45us/step).
//   VGPR: GEMM1 W1[4][512n][128k] i8 (128 regs) + mu_q[128n][512k] i8 (32 regs)
//   LDS (dynamic 150016B): mu_p + ls_p (128KB, XOR-swizzled) + t (16x1040) + z (16x144)
__global__ __attribute__((amdgpu_flat_work_group_size(512, 512)))
           __attribute__((amdgpu_waves_per_eu(2, 2)))
void zrec_i8(
    const unsigned short* __restrict__ preP, const unsigned short* __restrict__ preQ, // [ns*B,1024] bf16
    const signed char* __restrict__ W1q,   // [4 mats][512 n][128 k]: f1p,f2p,f1q,f2q
    const signed char* __restrict__ W2q,   // [3 mats][128 n][512 k]: mu_p, ls_p, mu_q
    const float* __restrict__ pmub, const float* __restrict__ plsb, const float* __restrict__ qmub,
    const float* __restrict__ eps,
    float* __restrict__ out_mu, float* __restrict__ out_ls, float* __restrict__ out_zn,
    signed char* __restrict__ z_state,     // [B][128] i8 persistent
    int t0, int nsteps)
{
  extern __shared__ __align__(16) char dyn[];
  char* ls_w = dyn;                        // 131072: [mu_p | ls_p][128 n][512 k] swizzled
  char* ls_t = dyn + 131072;               // 16 x 1040 (cols: t_p 0-511, t_q 512-1023, pad)
  char* ls_z = dyn + 131072 + 16640;       // 16 x 144

  const int tid = threadIdx.x, wave = tid >> 6, lane = tid & 63;
  const int col_l = lane & 15, kg = lane >> 4;
  const int brow0 = blockIdx.x * 16;
  const int d  = wave >> 2;                // dblock: 0=posterior, 1=prior
  const int cb = (wave & 3) * 128;         // GEMM1 col base (within 512 hid)
  const int hc = wave * 16 + col_l;        // GEMM2 head column (0..127)

  const float DS1 = (10.0f/127.0f) * (5.0f/(127.0f*19.59591794f)); // z-scale * W1-scale
  const float DS2 = (1.0f/127.0f)  * (5.0f/(127.0f*22.62741700f)); // t-scale * W2-scale

  // GEMM1 weights -> VGPR (this wave: both f1 and f2 of dblock d, cols cb..cb+127)
  i32x4 w1f[2][8][2];
  #pragma unroll
  for (int f=0; f<2; f++){
    int m = d*2 + f;
    #pragma unroll
    for (int j=0; j<8; j++){
      int n = cb + j*16 + col_l;
      const signed char* base = W1q + ((size_t)(m*512 + n) << 7) + kg*16;
      w1f[f][j][0] = *(const i32x4*)(base);
      w1f[f][j][1] = *(const i32x4*)(base + 64);
    }
  }
  // mu_q weights -> VGPR (this wave's 16 head cols)
  i32x4 wq[8];
  #pragma unroll
  for (int ks=0; ks<8; ks++)
    wq[ks] = *(const i32x4*)(W2q + ((size_t)(2*128 + hc) << 9) + ks*64 + kg*16);

  const float bp = pmub[hc], bl = plsb[hc], bq = qmub[hc];

  // fill LDS weights (mu_p, ls_p) with XOR swizzle on k
  for (int i = tid; i < 8192; i += 512){
    int m = i >> 12, rest = i & 4095, n = rest >> 5, k16 = (rest & 31) << 4;
    i32x4 v = *(const i32x4*)(W2q + ((size_t)(m*128 + n) << 9) + k16);
    *(i32x4*)(ls_w + (m << 16) + (n << 9) + (k16 ^ ((n & 7) << 4))) = v;
  }
  // init z
  if (t0 == 0){
    for (int i = tid; i < 2304; i += 512) ls_z[i] = 0;
  } else {
    for (int i = tid; i < 2048; i += 512){
      int row = i >> 7, col = i & 127;
      ls_z[row*144 + col] = z_state[(size_t)(brow0 + row)*128 + col];
    }
  }
  __syncthreads();

  const unsigned short* pre = d ? preQ : preP;

  // eps prefetch for step 0
  float er0[4];
  {
    size_t g0 = (size_t)t0*BATCH + brow0 + kg*4;
    #pragma unroll
    for (int r=0; r<4; r++) er0[r] = eps[(g0 + r)*STATE + hc];
  }

  for (int tl = 0; tl < nsteps; ++tl){
    // GEMM1 A-frags (z, i8)
    i32x4 zf0 = *(const i32x4*)(ls_z + col_l*144 + kg*16);
    i32x4 zf1 = *(const i32x4*)(ls_z + col_l*144 + 64 + kg*16);
    const unsigned short* pb = pre + ((size_t)(tl*BATCH) + brow0 + kg*4) * 1024;

    // two halves: issue the half's 32 pv loads FIRST, then MFMAs (latency overlap)
    #pragma unroll
    for (int h = 0; h < 2; h++){
      unsigned short pv[2][2][2][4];   // [qq][f][nt][r]
      #pragma unroll
      for (int qq=0; qq<2; qq++){
        int c0 = cb + (h*2 + qq)*32;
        #pragma unroll
        for (int f=0; f<2; f++)
          #pragma unroll
          for (int nt=0; nt<2; nt++)
            #pragma unroll
            for (int r=0; r<4; r++)
              pv[qq][f][nt][r] = pb[(size_t)r*1024 + f*512 + c0 + nt*16 + col_l];
      }
      #pragma unroll
      for (int qq=0; qq<2; qq++){
        int q = h*2 + qq;
        int c0 = cb + q*32;
        i32x4 acc[2][2];
        const i32x4 zz = {0,0,0,0};
        acc[0][0]=zz; acc[0][1]=zz; acc[1][0]=zz; acc[1][1]=zz;
        #pragma unroll
        for (int f=0; f<2; f++)
          #pragma unroll
          for (int nt=0; nt<2; nt++){
            acc[f][nt] = mfma_i8(zf0, w1f[f][q*2+nt][0], acc[f][nt]);
            acc[f][nt] = mfma_i8(zf1, w1f[f][q*2+nt][1], acc[f][nt]);
          }
        #pragma unroll
        for (int nt=0; nt<2; nt++)
          #pragma unroll
          for (int r=0; r<4; r++){
            float h1 = (float)acc[0][nt][r] * DS1 + bf2f(pv[qq][0][nt][r]);
            float h2 = (float)acc[1][nt][r] * DS1 + bf2f(pv[qq][1][nt][r]);
            float tv = fast_tanh(h1) * fast_sig(h2);
            float tq = fminf(fmaxf(rintf(tv * 127.0f), -127.0f), 127.0f);
            ls_t[(kg*4 + r)*1040 + d*512 + c0 + nt*16 + col_l] = (signed char)(int)tq;
          }
      }
    }
    __syncthreads();    // t visible

    // prefetch eps for NEXT step (overlaps GEMM2)
    float er1[4];
    {
      int nx = (tl+1 < nsteps) ? tl+1 : tl;
      size_t gn = (size_t)(t0 + nx)*BATCH + brow0 + kg*4;
      #pragma unroll
      for (int r=0; r<4; r++) er1[r] = eps[(gn + r)*STATE + hc];
    }

    // GEMM2: heads (K=512), A from LDS t, B: mu_p/ls_p LDS, mu_q VGPR
    i32x4 amp = {0,0,0,0}, als = {0,0,0,0}, amq = {0,0,0,0};
    #pragma unroll
    for (int ks=0; ks<8; ks++){
      i32x4 Ap = *(const i32x4*)(ls_t + col_l*1040 + ks*64 + kg*16);
      i32x4 Aq = *(const i32x4*)(ls_t + col_l*1040 + 512 + ks*64 + kg*16);
      int ko = (ks*64 + kg*16) ^ ((hc & 7) << 4);
      i32x4 Bp = *(const i32x4*)(ls_w + (hc << 9) + ko);
      i32x4 Bl = *(const i32x4*)(ls_w + 65536 + (hc << 9) + ko);
      amp = mfma_i8(Ap, Bp, amp);
      als = mfma_i8(Ap, Bl, als);
      amq = mfma_i8(Aq, wq[ks], amq);
    }
    // epilogue: mu, ls, z
    size_t growr = (size_t)(t0 + tl)*BATCH + brow0 + kg*4;
    #pragma unroll
    for (int r=0; r<4; r++){
      float mu = ((float)amq[r] * DS2 + bq) + ((float)amp[r] * DS2 + bp);
      float ls = (float)als[r] * DS2 + bl;
      float z  = mu + __expf(0.5f * ls) * er0[r];
      int row = kg*4 + r;
      out_mu[(growr + r)*STATE + hc] = mu;
      out_ls[(growr + r)*STATE + hc] = ls;
      if (t0 + tl == LSEQ-1) out_zn[(size_t)(brow0 + row)*STATE + hc] = z;
      float zq = fminf(fmaxf(rintf(z * 12.7f), -127.0f), 127.0f);
      ls_z[row*144 + hc] = (signed char)(int)zq;
    }
    #pragma unroll
    for (int r=0; r<4; r++) er0[r] = er1[r];
    __syncthreads();    // z visible; t reusable
  }

  // persist z state (i8)
  for (int i = tid; i < 2048; i += 512){
    int row = i >> 7, col = i & 127;
    z_state[(size_t)(brow0 + row)*128 + col] = ls_z[row*144 + col];
  }
}

// ---------------- host launcher ----------------
extern "C" void kernel_launch(void* const* d_in, const int* in_sizes, int n_in,
                              void* d_out, int out_size, void* d_ws, size_t ws_size,
                              hipStream_t stream)
{
  const float* ext = (const float*)d_in[0];
  const float* obs = (const float*)d_in[1];
  const float* eps = (const float*)d_in[2];
  const float* Wu  = (const float*)d_in[3];
  const float* bu  = (const float*)d_in[4];
  const float* Wx  = (const float*)d_in[5];
  const float* bx  = (const float*)d_in[6];
  const float* W_ih= (const float*)d_in[7];
  const float* b_ih= (const float*)d_in[8];
  const float* W_hh= (const float*)d_in[9];
  const float* b_hh= (const float*)d_in[10];
  const float* Wa1 = (const float*)d_in[11];
  const float* ba1 = (const float*)d_in[12];
  const float* Wa2 = (const float*)d_in[13];
  const float* ba2 = (const float*)d_in[14];
  const float* pf1W= (const float*)d_in[15]; const float* pf1b = (const float*)d_in[16];
  const float* pf2W= (const float*)d_in[17]; const float* pf2b = (const float*)d_in[18];
  const float* pmuW= (const float*)d_in[19]; const float* pmub = (const float*)d_in[20];
  const float* plsW= (const float*)d_in[21]; const float* plsb = (const float*)d_in[22];
  const float* qf1W= (const float*)d_in[23]; const float* qf1b = (const float*)d_in[24];
  const float* qf2W= (const float*)d_in[25]; const float* qf2b = (const float*)d_in[26];
  const float* qmuW= (const float*)d_in[27]; const float* qmub = (const float*)d_in[28];

  int NC = 0;
  const int cands[7] = {1,2,4,8,16,32,64};
  size_t rows = 0;
  for (int ci=0; ci<7; ci++){
    size_t r = (size_t)(LSEQ/cands[ci])*BATCH;
    size_t elems = 1600000 + r*3072;
    if (elems * 2 <= ws_size){ NC = cands[ci]; rows = r; break; }
  }
  if (!NC) return;
  const int nsteps = LSEQ/NC;
  const int gx = (int)(rows/128);

  unsigned short* ws = (unsigned short*)d_ws;
  size_t off = 0;
  auto alloc = [&](size_t elems){
    unsigned short* p = ws + off;
    off += (elems + 127) & ~(size_t)127;
    return p;
  };

  unsigned short* Wu_t  = alloc(64*256);
  unsigned short* Wx_t  = alloc(64*256);
  unsigned short* Wih_t = alloc(256*256);
  unsigned short* Whh_t = alloc(256*256);
  unsigned short* Wa1_t = alloc(512*256);
  unsigned short* Wa2_t = alloc(256*256);
  unsigned short* fAp   = alloc(1024*256);     // [f1(512) | f2(512)] x [256 k]
  unsigned short* fAq   = alloc(1024*256);
  signed char*    W1q   = (signed char*)alloc(131072);  // 262144 B
  signed char*    W2q   = (signed char*)alloc(98304);   // 196608 B
  unsigned short* d_state = alloc(256*256);
  signed char*    z_state = (signed char*)alloc(16384); // 32768 B
  unsigned short* bufA  = alloc(rows*256);
  unsigned short* bufB  = alloc(rows*256);
  unsigned short* bufC  = alloc(rows*512);
  unsigned short* preP  = alloc(rows*1024);
  unsigned short* preQ  = alloc(rows*1024);
  if (off * sizeof(unsigned short) > ws_size) return;

  float* out_mu = (float*)d_out;
  float* out_ls = out_mu + (size_t)LSEQ*BATCH*STATE;
  float* out_dn = out_ls + (size_t)LSEQ*BATCH*STATE;
  float* out_zn = out_dn + (size_t)BATCH*KDIM;

  WDescs wd;
  int wi = 0;
  auto add = [&](const float* s, unsigned short* dst, int Kk, int Nn, int ld, int ro, int co){
    wd.d[wi].src = s; wd.d[wi].dst = dst; wd.d[wi].K = Kk; wd.d[wi].N = Nn;
    wd.d[wi].ld = ld; wd.d[wi].rowoff = ro; wd.d[wi].coloff = co; wi++;
  };
  add(Wu,   Wu_t,  64, 256, 256, 0, 0);
  add(Wx,   Wx_t,  64, 256, 256, 0, 0);
  add(W_ih, Wih_t, 256, 256, 256, 0, 0);
  add(W_hh, Whh_t, 256, 256, 256, 0, 0);
  add(Wa1,  Wa1_t, 512, 256, 256, 0, 0);
  add(Wa2,  Wa2_t, 256, 256, 256, 0, 0);
  add(pf1W, fAp,            256, 512, 512, 128, 0);
  add(pf2W, fAp + 512*256,  256, 512, 512, 128, 0);
  add(qf1W, fAq,            256, 512, 512, 128, 0);
  add(qf2W, fAq + 512*256,  256, 512, 512, 128, 0);

  const float INV1 = 127.0f * 19.59591794f / 5.0f;  // 1/s for fan_in 384 mats
  const float INV2 = 127.0f * 22.62741700f / 5.0f;  // 1/s for fan_in 512 mats
  QDescs qd;
  auto addq = [&](int i, const float* s, signed char* dst, int Kk, int Nn, int ld, float is){
    qd.d[i].src = s; qd.d[i].dst = dst; qd.d[i].K = Kk; qd.d[i].N = Nn;
    qd.d[i].ld = ld; qd.d[i].inv_s = is;
  };
  addq(0, pf1W, W1q + 0*65536, 128, 512, 512, INV1);
  addq(1, pf2W, W1q + 1*65536, 128, 512, 512, INV1);
  addq(2, qf1W, W1q + 2*65536, 128, 512, 512, INV1);
  addq(3, qf2W, W1q + 3*65536, 128, 512, 512, INV1);
  addq(4, pmuW, W2q + 0*65536, 512, 128, 128, INV2);
  addq(5, plsW, W2q + 1*65536, 512, 128, 128, INV2);
  addq(6, qmuW, W2q + 2*65536, 512, 128, 128, INV2);

  convert_weights<<<dim3(512,10), 256, 0, stream>>>(wd);
  convert_q8<<<dim3(256,7), 256, 0, stream>>>(qd);

  hipFuncSetAttribute((const void*)zrec_i8,
                      hipFuncAttributeMaxDynamicSharedMemorySize, 150016);

  for (int c=0; c<NC; ++c){
    const int t0 = c * nsteps;
    const size_t row0 = (size_t)t0 * BATCH;

    GArgs e{};
    e.g[0] = GArg{ext + row0*64, Wu_t, bu, bu, bufA, 64, 256, 0,   64, 1, 1};
    e.g[1] = GArg{obs + row0*64, Wx_t, bx, bx, bufC, 64, 512, 256, 64, 1, 1};
    gemm_multi<<<dim3(gx,2,2), 256, 0, stream>>>(e);

    GArgs rn{};
    rn.g[0] = GArg{bufA, Wih_t, b_ih, b_ih, bufB, 256, 256, 0, 256, 0, 0};
    gemm_multi<<<dim3(gx,2,1), 256, 0, stream>>>(rn);

    rnn_chunk<<<16, 256, 0, stream>>>(bufB, Whh_t, b_hh, bufC, out_dn, d_state, t0, nsteps);

    GArgs a1{};
    a1.g[0] = GArg{bufC, Wa1_t, ba1, ba1, bufA, 512, 256, 0, 512, 1, 0};
    gemm_multi<<<dim3(gx,2,1), 256, 0, stream>>>(a1);

    GArgs a2{};
    a2.g[0] = GArg{bufA, Wa2_t, ba2, ba2, bufB, 256, 256, 0, 256, 0, 0};
    gemm_multi<<<dim3(gx,2,1), 256, 0, stream>>>(a2);

    GArgs pr{};
    pr.g[0] = GArg{bufB, fAp, pf1b, pf2b, preP, 256, 1024, 0, 256, 0, 0};
    pr.g[1] = GArg{bufC, fAq, qf1b, qf2b, preQ, 512, 1024, 0, 256, 0, 0};
    gemm_multi<<<dim3(gx,8,2), 256, 0, stream>>>(pr);

    zrec_i8<<<16, 512, 150016, stream>>>(preP, preQ, W1q, W2q,
                                         pmub, plsb, qmub, eps, out_mu, out_ls, out_zn,
                                         z_state, t0, nsteps);
  }
}

// Round 10
// 5960.902 us; speedup vs baseline: 1.1025x; 1.0426x over previous
//
#include <hip/hip_runtime.h>

#define LSEQ 512
#define BATCH 256
#define KDIM 256
#define STATE 128

using f32x4  = __attribute__((ext_vector_type(4))) float;
using short8 = __attribute__((ext_vector_type(8))) short;
using i32x4  = __attribute__((ext_vector_type(4))) int;

__device__ __forceinline__ float bf2f(unsigned short u){
  return __uint_as_float(((unsigned int)u) << 16);
}
__device__ __forceinline__ unsigned short f2bf(float f){
  unsigned int u = __float_as_uint(f);
  u += 0x7FFFu + ((u >> 16) & 1u);   // RNE
  return (unsigned short)(u >> 16);
}
__device__ __forceinline__ float fast_tanh(float x){
  float ax = fabsf(x);
  float e  = __expf(2.0f * ax);
  float t  = 1.0f - 2.0f / (e + 1.0f);
  return copysignf(t, x);
}
__device__ __forceinline__ float fast_sig(float x){
  return 1.0f / (1.0f + __expf(-x));
}
__device__ __forceinline__ f32x4 mfma16(short8 a, short8 b, f32x4 c){
  return __builtin_amdgcn_mfma_f32_16x16x32_bf16(a, b, c, 0, 0, 0);
}
__device__ __forceinline__ i32x4 mfma_i8(i32x4 a, i32x4 b, i32x4 c){
  return __builtin_amdgcn_mfma_i32_16x16x64_i8(a, b, c, 0, 0, 0);
}

__device__ __forceinline__ int swz128 (int b){ return b ^ ((((b >> 7) & 7) << 4)); }
__device__ __forceinline__ int swz512 (int b){ return b ^ ((((b >> 9) & 7) << 4)); }

// ---------------- weight convert: f32 src[rowoff+k][coloff+n] -> bf16 dst[n*K+k] ----------------
struct WDesc { const float* src; unsigned short* dst; int K, N, ld, rowoff, coloff; };
struct WDescs { WDesc d[10]; };

__global__ __launch_bounds__(256,4) void convert_weights(WDescs ds){
  WDesc w = ds.d[blockIdx.y];
  int total = w.K * w.N;
  int idx = blockIdx.x * 256 + threadIdx.x;
  if (idx < total){
    int n = idx / w.K;
    int k = idx - n * w.K;
    w.dst[idx] = f2bf(w.src[(size_t)(w.rowoff + k) * w.ld + w.coloff + n]);
  }
}

// ---------------- weight convert: f32 -> int8 transposed [n][k], static scale ----------------
struct QDesc { const float* src; signed char* dst; int K, N, ld; float inv_s; };
struct QDescs { QDesc d[7]; };

__global__ __launch_bounds__(256,4) void convert_q8(QDescs ds){
  QDesc w = ds.d[blockIdx.y];
  int idx = blockIdx.x * 256 + threadIdx.x;
  if (idx < w.K * w.N){
    int n = idx / w.K;
    int k = idx - n * w.K;
    float v = w.src[(size_t)k * w.ld + n] * w.inv_s;
    v = fminf(fmaxf(rintf(v), -127.0f), 127.0f);
    w.dst[idx] = (signed char)(int)v;
  }
}

// ---------------- multi-descriptor bf16 MFMA GEMM ----------------
// perm=1: store columns permuted for zrec's vectorized reads:
//   cf = col & 511; scol = (col&512) + (cf>>7)*128 + (cf&15)*8 + ((cf>>4)&7)
struct GArg {
  const void* A; const unsigned short* Bt; const float* bias; const float* bias2;
  unsigned short* C; int lda, ldc, coff, K, act, a_f32, perm;
};
struct GArgs { GArg g[4]; };

__global__ __launch_bounds__(256,2) void gemm_multi(GArgs args){
  GArg ga = args.g[blockIdx.z];
  __shared__ __align__(16) unsigned short lsA[128*64];
  __shared__ __align__(16) unsigned short lsB[128*64];
  const int tid  = threadIdx.x;
  const int wave = tid >> 6, lane = tid & 63;
  const int col_l = lane & 15, rgrp = lane >> 4;
  const int m0 = blockIdx.x * 128, n0 = blockIdx.y * 128;
  const int wm = (wave >> 1) * 64, wn = (wave & 1) * 64;

  f32x4 acc[4][4];
  const f32x4 z4 = {0.f,0.f,0.f,0.f};
  #pragma unroll
  for (int i=0;i<4;i++){ acc[i][0]=z4; acc[i][1]=z4; acc[i][2]=z4; acc[i][3]=z4; }

  const int srow = tid >> 1;
  const int sbe  = (tid & 1) * 32;

  for (int k0 = 0; k0 < ga.K; k0 += 64){
    uint4 av[4], bv[4];
    if (ga.a_f32){
      const float* Ap = (const float*)ga.A + (size_t)(m0 + srow) * ga.lda + k0 + sbe;
      uint4 fv[8];
      #pragma unroll
      for (int i=0;i<8;i++) fv[i] = *(const uint4*)((const char*)Ap + i*16);
      #pragma unroll
      for (int i=0;i<4;i++){
        const float* f = (const float*)&fv[i*2];
        uint4 o;
        o.x = (unsigned)f2bf(f[0]) | ((unsigned)f2bf(f[1]) << 16);
        o.y = (unsigned)f2bf(f[2]) | ((unsigned)f2bf(f[3]) << 16);
        o.z = (unsigned)f2bf(f[4]) | ((unsigned)f2bf(f[5]) << 16);
        o.w = (unsigned)f2bf(f[6]) | ((unsigned)f2bf(f[7]) << 16);
        av[i] = o;
      }
    } else {
      const unsigned short* Ap = (const unsigned short*)ga.A + (size_t)(m0 + srow) * ga.lda + k0 + sbe;
      #pragma unroll
      for (int i=0;i<4;i++) av[i] = *(const uint4*)((const char*)Ap + i*16);
    }
    const unsigned short* Bp = ga.Bt + (size_t)(n0 + srow) * ga.K + k0 + sbe;
    #pragma unroll
    for (int i=0;i<4;i++) bv[i] = *(const uint4*)((const char*)Bp + i*16);

    __syncthreads();
    #pragma unroll
    for (int i=0;i<4;i++){
      *(uint4*)((char*)lsA + swz128(srow*128 + sbe*2 + i*16)) = av[i];
      *(uint4*)((char*)lsB + swz128(srow*128 + sbe*2 + i*16)) = bv[i];
    }
    __syncthreads();
    #pragma unroll
    for (int kk=0; kk<2; kk++){
      short8 af[4], bfr[4];
      #pragma unroll
      for (int mt=0; mt<4; mt++)
        af[mt] = *(const short8*)((const char*)lsA + swz128((wm + mt*16 + col_l)*128 + kk*64 + rgrp*16));
      #pragma unroll
      for (int nt=0; nt<4; nt++)
        bfr[nt] = *(const short8*)((const char*)lsB + swz128((wn + nt*16 + col_l)*128 + kk*64 + rgrp*16));
      #pragma unroll
      for (int mt=0; mt<4; mt++)
        #pragma unroll
        for (int nt=0; nt<4; nt++)
          acc[mt][nt] = mfma16(af[mt], bfr[nt], acc[mt][nt]);
    }
  }
  #pragma unroll
  for (int nt=0; nt<4; nt++){
    int col = n0 + wn + nt*16 + col_l;
    const float* bsrc = (col < 512) ? ga.bias : ga.bias2;
    float bb = bsrc ? bsrc[col & 511] : 0.0f;
    int scol = col;
    if (ga.perm){
      int cf = col & 511;
      scol = (col & 512) + ((cf >> 7) << 7) + ((cf & 15) << 3) + ((cf >> 4) & 7);
    }
    #pragma unroll
    for (int mt=0; mt<4; mt++){
      #pragma unroll
      for (int r=0; r<4; r++){
        int row = m0 + wm + mt*16 + rgrp*4 + r;
        float v = acc[mt][nt][r] + bb;
        if (ga.act == 1) v = fast_tanh(v);
        ga.C[(size_t)row * ga.ldc + ga.coff + scol] = f2bf(v);
      }
    }
  }
}

// ---------------- phase B: tanh-RNN chunk, W_hh held in VGPRs ----------------
__global__ __launch_bounds__(256,1) void rnn_chunk(
    const unsigned short* __restrict__ rnn_in,
    const unsigned short* __restrict__ Whh_t,
    const float* __restrict__ b_hh,
    unsigned short* __restrict__ cat_d,
    float* __restrict__ dn_out,
    unsigned short* __restrict__ d_state,
    int t0, int nsteps)
{
  __shared__ __align__(16) unsigned short dls[16*256];
  const int tid = threadIdx.x, wave = tid >> 6, lane = tid & 63;
  const int col_l = lane & 15, rgrp = lane >> 4;
  const int brow0 = blockIdx.x * 16;
  const int ncol = wave * 64;

  short8 bfr[4][8];
  #pragma unroll
  for (int nt=0; nt<4; nt++){
    const unsigned short* bp = Whh_t + (size_t)(ncol + nt*16 + col_l) * 256;
    #pragma unroll
    for (int kk=0; kk<8; kk++)
      bfr[nt][kk] = *(const short8*)(bp + kk*32 + rgrp*8);
  }
  float bias[4];
  #pragma unroll
  for (int nt=0; nt<4; nt++) bias[nt] = b_hh[ncol + nt*16 + col_l];

  if (t0 == 0){
    for (int i = tid; i < 16*256; i += 256){
      int row = i >> 8, col = i & 255;
      *(unsigned short*)((char*)dls + swz512(row*512 + col*2)) = 0;
    }
  } else {
    const unsigned short* ds = d_state + (size_t)brow0 * 256;
    for (int i = tid; i < 16*256; i += 256){
      int row = i >> 8, col = i & 255;
      *(unsigned short*)((char*)dls + swz512(row*512 + col*2)) = ds[row*256 + col];
    }
  }
  __syncthreads();

  for (int tl=0; tl<nsteps; tl++){
    unsigned short rv[4][4];
    const unsigned short* rp = rnn_in + (size_t)(tl*BATCH + brow0) * 256;
    #pragma unroll
    for (int nt=0; nt<4; nt++)
      #pragma unroll
      for (int r=0; r<4; r++)
        rv[nt][r] = rp[(size_t)(rgrp*4 + r)*256 + ncol + nt*16 + col_l];

    f32x4 acc[4];
    const f32x4 z4 = {0.f,0.f,0.f,0.f};
    acc[0]=z4; acc[1]=z4; acc[2]=z4; acc[3]=z4;
    #pragma unroll
    for (int kk=0; kk<8; kk++){
      short8 af = *(const short8*)((const char*)dls + swz512((lane & 15)*512 + kk*64 + rgrp*16));
      #pragma unroll
      for (int nt=0; nt<4; nt++)
        acc[nt] = mfma16(af, bfr[nt][kk], acc[nt]);
    }
    __syncthreads();
    #pragma unroll
    for (int nt=0; nt<4; nt++){
      #pragma unroll
      for (int r=0; r<4; r++){
        float h = acc[nt][r] + bf2f(rv[nt][r]) + bias[nt];
        float d = fast_tanh(h);
        int row = rgrp*4 + r, col = ncol + nt*16 + col_l;
        unsigned short db = f2bf(d);
        *(unsigned short*)((char*)dls + swz512(row*512 + col*2)) = db;
        cat_d[(size_t)(tl*BATCH + brow0 + row)*512 + col] = db;
        if (t0 + tl == LSEQ-1) dn_out[(size_t)(brow0 + row)*256 + col] = d;
      }
    }
    __syncthreads();
  }
  unsigned short* dso = d_state + (size_t)brow0 * 256;
  for (int i = tid; i < 16*256; i += 256){
    int row = i >> 8, col = i & 255;
    dso[row*256 + col] = *(const unsigned short*)((const char*)dls + swz512(row*512 + col*2));
  }
}

// ---------------- phase D: SINGLE-CU z recurrence, int8 weights, no cross-CU sync ----------------
// 32 wgs x 8 batch rows (rows 8-15 of each 16-row tile = bounded garbage, masked
// at stores); 512 threads. Weights asm-PINNED into VGPRs (r9: allocator
// rematerialized the loads in-loop at VGPR_Count=128 despite waves_per_eu(2,2)).
// Pre-activations stored PERMUTED by the prelude so each thread reads 8x16B.
__global__ __attribute__((amdgpu_flat_work_group_size(512, 512)))
           __attribute__((amdgpu_waves_per_eu(2, 2)))
void zrec_i8(
    const unsigned short* __restrict__ preP, const unsigned short* __restrict__ preQ, // [ns*B,1024] bf16 permuted
    const signed char* __restrict__ W1q,   // [4 mats][512 n][128 k]: f1p,f2p,f1q,f2q
    const signed char* __restrict__ W2q,   // [3 mats][128 n][512 k]: mu_p, ls_p, mu_q
    const float* __restrict__ pmub, const float* __restrict__ plsb, const float* __restrict__ qmub,
    const float* __restrict__ eps,
    float* __restrict__ out_mu, float* __restrict__ out_ls, float* __restrict__ out_zn,
    signed char* __restrict__ z_state,     // [B][128] i8 persistent
    int t0, int nsteps)
{
  extern __shared__ __align__(16) char dyn[];
  char* ls_w = dyn;                        // 131072: [mu_p | ls_p][128 n][512 k] swizzled
  char* ls_t = dyn + 131072;               // 16 x 1040 (cols: t_p 0-511, t_q 512-1023, pad)
  char* ls_z = dyn + 131072 + 16640;       // 16 x 144

  const int tid = threadIdx.x, wave = tid >> 6, lane = tid & 63;
  const int col_l = lane & 15, kg = lane >> 4;
  const int brow0 = blockIdx.x * 8;        // 8 valid rows per wg
  const int d  = wave >> 2;                // dblock: 0=posterior, 1=prior
  const int cb = (wave & 3) * 128;         // GEMM1 col base (within 512 hid)
  const int hc = wave * 16 + col_l;        // GEMM2 head column (0..127)
  const int orow = kg * 4;                 // output row base; valid iff kg<2

  const float DS1 = (10.0f/127.0f) * (5.0f/(127.0f*19.59591794f)); // z-scale * W1-scale
  const float DS2 = (1.0f/127.0f)  * (5.0f/(127.0f*22.62741700f)); // t-scale * W2-scale

  // GEMM1 weights -> VGPR, then PIN (asm-defined => non-rematerializable)
  i32x4 w1f[2][8][2];
  #pragma unroll
  for (int f=0; f<2; f++){
    int m = d*2 + f;
    #pragma unroll
    for (int j=0; j<8; j++){
      int n = cb + j*16 + col_l;
      const signed char* base = W1q + ((size_t)(m*512 + n) << 7) + kg*16;
      w1f[f][j][0] = *(const i32x4*)(base);
      w1f[f][j][1] = *(const i32x4*)(base + 64);
      asm volatile("" : "+v"(w1f[f][j][0]), "+v"(w1f[f][j][1]));
    }
  }
  // mu_q weights -> VGPR, pinned
  i32x4 wq[8];
  #pragma unroll
  for (int ks=0; ks<8; ks++){
    wq[ks] = *(const i32x4*)(W2q + ((size_t)(2*128 + hc) << 9) + ks*64 + kg*16);
    asm volatile("" : "+v"(wq[ks]));
  }

  const float bp = pmub[hc], bl = plsb[hc], bq = qmub[hc];

  // fill LDS weights (mu_p, ls_p) with XOR swizzle on k
  for (int i = tid; i < 8192; i += 512){
    int m = i >> 12, rest = i & 4095, n = rest >> 5, k16 = (rest & 31) << 4;
    i32x4 v = *(const i32x4*)(W2q + ((size_t)(m*128 + n) << 9) + k16);
    *(i32x4*)(ls_w + (m << 16) + (n << 9) + (k16 ^ ((n & 7) << 4))) = v;
  }
  // init z (rows 8-15 mirror rows 0-7; they only feed masked garbage lanes)
  if (t0 == 0){
    for (int i = tid; i < 2304; i += 512) ls_z[i] = 0;
  } else {
    for (int i = tid; i < 2048; i += 512){
      int row = i >> 7, col = i & 127;
      ls_z[row*144 + col] = z_state[(size_t)(brow0 + (row & 7))*128 + col];
    }
  }
  __syncthreads();

  const unsigned short* pre = d ? preQ : preP;

  // eps prefetch for step 0 (rows clamped into the wg's 8 valid rows)
  float er0[4];
  #pragma unroll
  for (int r=0; r<4; r++){
    int rowc = (orow + r) & 7;
    er0[r] = eps[((size_t)t0*BATCH + brow0 + rowc)*STATE + hc];
  }

  for (int tl = 0; tl < nsteps; ++tl){
    // vectorized pre loads: 8 x 16B per thread (permuted layout)
    i32x4 pvv[2][4];
    const unsigned short* pb = pre + ((size_t)tl*BATCH + brow0)*1024;
    #pragma unroll
    for (int f=0; f<2; f++)
      #pragma unroll
      for (int r=0; r<4; r++){
        int rowc = (orow + r) & 7;
        pvv[f][r] = *(const i32x4*)(pb + (size_t)rowc*1024 + f*512 + cb + col_l*8);
      }

    // GEMM1 A-frags (z, i8)
    i32x4 zf0 = *(const i32x4*)(ls_z + col_l*144 + kg*16);
    i32x4 zf1 = *(const i32x4*)(ls_z + col_l*144 + 64 + kg*16);

    #pragma unroll
    for (int q = 0; q < 4; q++){
      int c0 = cb + q*32;
      i32x4 acc[2][2];
      const i32x4 zz = {0,0,0,0};
      acc[0][0]=zz; acc[0][1]=zz; acc[1][0]=zz; acc[1][1]=zz;
      #pragma unroll
      for (int f=0; f<2; f++)
        #pragma unroll
        for (int nt=0; nt<2; nt++){
          acc[f][nt] = mfma_i8(zf0, w1f[f][q*2+nt][0], acc[f][nt]);
          acc[f][nt] = mfma_i8(zf1, w1f[f][q*2+nt][1], acc[f][nt]);
        }
      #pragma unroll
      for (int nt=0; nt<2; nt++){
        const int j = q*2 + nt;
        #pragma unroll
        for (int r=0; r<4; r++){
          unsigned wa = (unsigned)pvv[0][r][j>>1];
          unsigned wb = (unsigned)pvv[1][r][j>>1];
          unsigned short ua = (j&1) ? (unsigned short)(wa >> 16) : (unsigned short)(wa & 0xffff);
          unsigned short ub = (j&1) ? (unsigned short)(wb >> 16) : (unsigned short)(wb & 0xffff);
          float h1 = (float)acc[0][nt][r] * DS1 + bf2f(ua);
          float h2 = (float)acc[1][nt][r] * DS1 + bf2f(ub);
          float tv = fast_tanh(h1) * fast_sig(h2);
          float tq = fminf(fmaxf(rintf(tv * 127.0f), -127.0f), 127.0f);
          ls_t[(kg*4 + r)*1040 + d*512 + c0 + nt*16 + col_l] = (signed char)(int)tq;
        }
      }
    }
    __syncthreads();    // t visible

    // prefetch eps for NEXT step (overlaps GEMM2)
    float er1[4];
    {
      int nx = (tl+1 < nsteps) ? tl+1 : tl;
      #pragma unroll
      for (int r=0; r<4; r++){
        int rowc = (orow + r) & 7;
        er1[r] = eps[((size_t)(t0 + nx)*BATCH + brow0 + rowc)*STATE + hc];
      }
    }

    // GEMM2: heads (K=512), A from LDS t, B: mu_p/ls_p LDS, mu_q VGPR
    i32x4 amp = {0,0,0,0}, als = {0,0,0,0}, amq = {0,0,0,0};
    #pragma unroll
    for (int ks=0; ks<8; ks++){
      i32x4 Ap = *(const i32x4*)(ls_t + col_l*1040 + ks*64 + kg*16);
      i32x4 Aq = *(const i32x4*)(ls_t + col_l*1040 + 512 + ks*64 + kg*16);
      int ko = (ks*64 + kg*16) ^ ((hc & 7) << 4);
      i32x4 Bp = *(const i32x4*)(ls_w + (hc << 9) + ko);
      i32x4 Bl = *(const i32x4*)(ls_w + 65536 + (hc << 9) + ko);
      amp = mfma_i8(Ap, Bp, amp);
      als = mfma_i8(Ap, Bl, als);
      amq = mfma_i8(Aq, wq[ks], amq);
    }
    // epilogue: mu, ls, z (stores masked to the 8 valid rows: kg<2)
    size_t growr = (size_t)(t0 + tl)*BATCH + brow0 + orow;
    #pragma unroll
    for (int r=0; r<4; r++){
      float mu = ((float)amq[r] * DS2 + bq) + ((float)amp[r] * DS2 + bp);
      float ls = (float)als[r] * DS2 + bl;
      float z  = mu + __expf(0.5f * ls) * er0[r];
      int row = orow + r;
      if (kg < 2){
        out_mu[(growr + r)*STATE + hc] = mu;
        out_ls[(growr + r)*STATE + hc] = ls;
        if (t0 + tl == LSEQ-1) out_zn[(size_t)(brow0 + row)*STATE + hc] = z;
      }
      float zq = fminf(fmaxf(rintf(z * 12.7f), -127.0f), 127.0f);
      ls_z[row*144 + hc] = (signed char)(int)zq;
    }
    #pragma unroll
    for (int r=0; r<4; r++) er0[r] = er1[r];
    __syncthreads();    // z visible; t reusable
  }

  // persist z state (8 valid rows)
  for (int i = tid; i < 1024; i += 512){
    int row = i >> 7, col = i & 127;
    z_state[(size_t)(brow0 + row)*128 + col] = ls_z[row*144 + col];
  }
}

// ---------------- host launcher ----------------
extern "C" void kernel_launch(void* const* d_in, const int* in_sizes, int n_in,
                              void* d_out, int out_size, void* d_ws, size_t ws_size,
                              hipStream_t stream)
{
  const float* ext = (const float*)d_in[0];
  const float* obs = (const float*)d_in[1];
  const float* eps = (const float*)d_in[2];
  const float* Wu  = (const float*)d_in[3];
  const float* bu  = (const float*)d_in[4];
  const float* Wx  = (const float*)d_in[5];
  const float* bx  = (const float*)d_in[6];
  const float* W_ih= (const float*)d_in[7];
  const float* b_ih= (const float*)d_in[8];
  const float* W_hh= (const float*)d_in[9];
  const float* b_hh= (const float*)d_in[10];
  const float* Wa1 = (const float*)d_in[11];
  const float* ba1 = (const float*)d_in[12];
  const float* Wa2 = (const float*)d_in[13];
  const float* ba2 = (const float*)d_in[14];
  const float* pf1W= (const float*)d_in[15]; const float* pf1b = (const float*)d_in[16];
  const float* pf2W= (const float*)d_in[17]; const float* pf2b = (const float*)d_in[18];
  const float* pmuW= (const float*)d_in[19]; const float* pmub = (const float*)d_in[20];
  const float* plsW= (const float*)d_in[21]; const float* plsb = (const float*)d_in[22];
  const float* qf1W= (const float*)d_in[23]; const float* qf1b = (const float*)d_in[24];
  const float* qf2W= (const float*)d_in[25]; const float* qf2b = (const float*)d_in[26];
  const float* qmuW= (const float*)d_in[27]; const float* qmub = (const float*)d_in[28];

  int NC = 0;
  const int cands[7] = {1,2,4,8,16,32,64};
  size_t rows = 0;
  for (int ci=0; ci<7; ci++){
    size_t r = (size_t)(LSEQ/cands[ci])*BATCH;
    size_t elems = 1600000 + r*3072;
    if (elems * 2 <= ws_size){ NC = cands[ci]; rows = r; break; }
  }
  if (!NC) return;
  const int nsteps = LSEQ/NC;
  const int gx = (int)(rows/128);

  unsigned short* ws = (unsigned short*)d_ws;
  size_t off = 0;
  auto alloc = [&](size_t elems){
    unsigned short* p = ws + off;
    off += (elems + 127) & ~(size_t)127;
    return p;
  };

  unsigned short* Wu_t  = alloc(64*256);
  unsigned short* Wx_t  = alloc(64*256);
  unsigned short* Wih_t = alloc(256*256);
  unsigned short* Whh_t = alloc(256*256);
  unsigned short* Wa1_t = alloc(512*256);
  unsigned short* Wa2_t = alloc(256*256);
  unsigned short* fAp   = alloc(1024*256);     // [f1(512) | f2(512)] x [256 k]
  unsigned short* fAq   = alloc(1024*256);
  signed char*    W1q   = (signed char*)alloc(131072);  // 262144 B
  signed char*    W2q   = (signed char*)alloc(98304);   // 196608 B
  unsigned short* d_state = alloc(256*256);
  signed char*    z_state = (signed char*)alloc(16384); // 32768 B
  unsigned short* bufA  = alloc(rows*256);
  unsigned short* bufB  = alloc(rows*256);
  unsigned short* bufC  = alloc(rows*512);
  unsigned short* preP  = alloc(rows*1024);
  unsigned short* preQ  = alloc(rows*1024);
  if (off * sizeof(unsigned short) > ws_size) return;

  float* out_mu = (float*)d_out;
  float* out_ls = out_mu + (size_t)LSEQ*BATCH*STATE;
  float* out_dn = out_ls + (size_t)LSEQ*BATCH*STATE;
  float* out_zn = out_dn + (size_t)BATCH*KDIM;

  WDescs wd;
  int wi = 0;
  auto add = [&](const float* s, unsigned short* dst, int Kk, int Nn, int ld, int ro, int co){
    wd.d[wi].src = s; wd.d[wi].dst = dst; wd.d[wi].K = Kk; wd.d[wi].N = Nn;
    wd.d[wi].ld = ld; wd.d[wi].rowoff = ro; wd.d[wi].coloff = co; wi++;
  };
  add(Wu,   Wu_t,  64, 256, 256, 0, 0);
  add(Wx,   Wx_t,  64, 256, 256, 0, 0);
  add(W_ih, Wih_t, 256, 256, 256, 0, 0);
  add(W_hh, Whh_t, 256, 256, 256, 0, 0);
  add(Wa1,  Wa1_t, 512, 256, 256, 0, 0);
  add(Wa2,  Wa2_t, 256, 256, 256, 0, 0);
  add(pf1W, fAp,            256, 512, 512, 128, 0);
  add(pf2W, fAp + 512*256,  256, 512, 512, 128, 0);
  add(qf1W, fAq,            256, 512, 512, 128, 0);
  add(qf2W, fAq + 512*256,  256, 512, 512, 128, 0);

  const float INV1 = 127.0f * 19.59591794f / 5.0f;  // 1/s for fan_in 384 mats
  const float INV2 = 127.0f * 22.62741700f / 5.0f;  // 1/s for fan_in 512 mats
  QDescs qd;
  auto addq = [&](int i, const float* s, signed char* dst, int Kk, int Nn, int ld, float is){
    qd.d[i].src = s; qd.d[i].dst = dst; qd.d[i].K = Kk; qd.d[i].N = Nn;
    qd.d[i].ld = ld; qd.d[i].inv_s = is;
  };
  addq(0, pf1W, W1q + 0*65536, 128, 512, 512, INV1);
  addq(1, pf2W, W1q + 1*65536, 128, 512, 512, INV1);
  addq(2, qf1W, W1q + 2*65536, 128, 512, 512, INV1);
  addq(3, qf2W, W1q + 3*65536, 128, 512, 512, INV1);
  addq(4, pmuW, W2q + 0*65536, 512, 128, 128, INV2);
  addq(5, plsW, W2q + 1*65536, 512, 128, 128, INV2);
  addq(6, qmuW, W2q + 2*65536, 512, 128, 128, INV2);

  convert_weights<<<dim3(512,10), 256, 0, stream>>>(wd);
  convert_q8<<<dim3(256,7), 256, 0, stream>>>(qd);

  hipFuncSetAttribute((const void*)zrec_i8,
                      hipFuncAttributeMaxDynamicSharedMemorySize, 150016);

  for (int c=0; c<NC; ++c){
    const int t0 = c * nsteps;
    const size_t row0 = (size_t)t0 * BATCH;

    GArgs e{};
    e.g[0] = GArg{ext + row0*64, Wu_t, bu, bu, bufA, 64, 256, 0,   64, 1, 1, 0};
    e.g[1] = GArg{obs + row0*64, Wx_t, bx, bx, bufC, 64, 512, 256, 64, 1, 1, 0};
    gemm_multi<<<dim3(gx,2,2), 256, 0, stream>>>(e);

    GArgs rn{};
    rn.g[0] = GArg{bufA, Wih_t, b_ih, b_ih, bufB, 256, 256, 0, 256, 0, 0, 0};
    gemm_multi<<<dim3(gx,2,1), 256, 0, stream>>>(rn);

    rnn_chunk<<<16, 256, 0, stream>>>(bufB, Whh_t, b_hh, bufC, out_dn, d_state, t0, nsteps);

    GArgs a1{};
    a1.g[0] = GArg{bufC, Wa1_t, ba1, ba1, bufA, 512, 256, 0, 512, 1, 0, 0};
    gemm_multi<<<dim3(gx,2,1), 256, 0, stream>>>(a1);

    GArgs a2{};
    a2.g[0] = GArg{bufA, Wa2_t, ba2, ba2, bufB, 256, 256, 0, 256, 0, 0, 0};
    gemm_multi<<<dim3(gx,2,1), 256, 0, stream>>>(a2);

    GArgs pr{};
    pr.g[0] = GArg{bufB, fAp, pf1b, pf2b, preP, 256, 1024, 0, 256, 0, 0, 1};
    pr.g[1] = GArg{bufC, fAq, qf1b, qf2b, preQ, 512, 1024, 0, 256, 0, 0, 1};
    gemm_multi<<<dim3(gx,8,2), 256, 0, stream>>>(pr);

    zrec_i8<<<32, 512, 150016, stream>>>(preP, preQ, W1q, W2q,
                                         pmub, plsb, qmub, eps, out_mu, out_ls, out_zn,
                                         z_state, t0, nsteps);
  }
}

// Round 11
// 5371.426 us; speedup vs baseline: 1.2235x; 1.1097x over previous
//
#include <hip/hip_runtime.h>

#define LSEQ 512
#define BATCH 256
#define KDIM 256
#define STATE 128

using f32x4  = __attribute__((ext_vector_type(4))) float;
using short8 = __attribute__((ext_vector_type(8))) short;
using i32x4  = __attribute__((ext_vector_type(4))) int;

__device__ __forceinline__ float bf2f(unsigned short u){
  return __uint_as_float(((unsigned int)u) << 16);
}
__device__ __forceinline__ unsigned short f2bf(float f){
  unsigned int u = __float_as_uint(f);
  u += 0x7FFFu + ((u >> 16) & 1u);   // RNE
  return (unsigned short)(u >> 16);
}
__device__ __forceinline__ float fast_tanh(float x){
  float ax = fabsf(x);
  float e  = __expf(2.0f * ax);
  float t  = 1.0f - 2.0f / (e + 1.0f);
  return copysignf(t, x);
}
__device__ __forceinline__ float fast_sig(float x){
  return 1.0f / (1.0f + __expf(-x));
}
__device__ __forceinline__ f32x4 mfma16(short8 a, short8 b, f32x4 c){
  return __builtin_amdgcn_mfma_f32_16x16x32_bf16(a, b, c, 0, 0, 0);
}
__device__ __forceinline__ i32x4 mfma_i8(i32x4 a, i32x4 b, i32x4 c){
  return __builtin_amdgcn_mfma_i32_16x16x64_i8(a, b, c, 0, 0, 0);
}

__device__ __forceinline__ int swz128 (int b){ return b ^ ((((b >> 7) & 7) << 4)); }
__device__ __forceinline__ int swz512 (int b){ return b ^ ((((b >> 9) & 7) << 4)); }

// ---------------- weight convert: f32 src[rowoff+k][coloff+n] -> bf16 dst[n*K+k] ----------------
struct WDesc { const float* src; unsigned short* dst; int K, N, ld, rowoff, coloff; };
struct WDescs { WDesc d[10]; };

__global__ __launch_bounds__(256,4) void convert_weights(WDescs ds){
  WDesc w = ds.d[blockIdx.y];
  int total = w.K * w.N;
  int idx = blockIdx.x * 256 + threadIdx.x;
  if (idx < total){
    int n = idx / w.K;
    int k = idx - n * w.K;
    w.dst[idx] = f2bf(w.src[(size_t)(w.rowoff + k) * w.ld + w.coloff + n]);
  }
}

// ---------------- weight convert: f32 -> int8 transposed [n][k], static scale ----------------
// kperm=1: dst position p holds source k = (p&~127)|((p&7)<<4)|((p>>3)&15)
// (matches zrec's permuted t layout; MFMA is k-permutation invariant when A,B agree)
struct QDesc { const float* src; signed char* dst; int K, N, ld; float inv_s; int kperm; };
struct QDescs { QDesc d[7]; };

__global__ __launch_bounds__(256,4) void convert_q8(QDescs ds){
  QDesc w = ds.d[blockIdx.y];
  int idx = blockIdx.x * 256 + threadIdx.x;
  if (idx < w.K * w.N){
    int n = idx / w.K;
    int p = idx - n * w.K;
    int k = p;
    if (w.kperm) k = (p & ~127) | ((p & 7) << 4) | ((p >> 3) & 15);
    float v = w.src[(size_t)k * w.ld + n] * w.inv_s;
    v = fminf(fmaxf(rintf(v), -127.0f), 127.0f);
    w.dst[idx] = (signed char)(int)v;
  }
}

// ---------------- multi-descriptor bf16 MFMA GEMM ----------------
// perm=1: store columns permuted for zrec's vectorized reads:
//   cf = col & 511; scol = (col&512) + (cf>>7)*128 + (cf&15)*8 + ((cf>>4)&7)
struct GArg {
  const void* A; const unsigned short* Bt; const float* bias; const float* bias2;
  unsigned short* C; int lda, ldc, coff, K, act, a_f32, perm;
};
struct GArgs { GArg g[4]; };

__global__ __launch_bounds__(256,2) void gemm_multi(GArgs args){
  GArg ga = args.g[blockIdx.z];
  __shared__ __align__(16) unsigned short lsA[128*64];
  __shared__ __align__(16) unsigned short lsB[128*64];
  const int tid  = threadIdx.x;
  const int wave = tid >> 6, lane = tid & 63;
  const int col_l = lane & 15, rgrp = lane >> 4;
  const int m0 = blockIdx.x * 128, n0 = blockIdx.y * 128;
  const int wm = (wave >> 1) * 64, wn = (wave & 1) * 64;

  f32x4 acc[4][4];
  const f32x4 z4 = {0.f,0.f,0.f,0.f};
  #pragma unroll
  for (int i=0;i<4;i++){ acc[i][0]=z4; acc[i][1]=z4; acc[i][2]=z4; acc[i][3]=z4; }

  const int srow = tid >> 1;
  const int sbe  = (tid & 1) * 32;

  for (int k0 = 0; k0 < ga.K; k0 += 64){
    uint4 av[4], bv[4];
    if (ga.a_f32){
      const float* Ap = (const float*)ga.A + (size_t)(m0 + srow) * ga.lda + k0 + sbe;
      uint4 fv[8];
      #pragma unroll
      for (int i=0;i<8;i++) fv[i] = *(const uint4*)((const char*)Ap + i*16);
      #pragma unroll
      for (int i=0;i<4;i++){
        const float* f = (const float*)&fv[i*2];
        uint4 o;
        o.x = (unsigned)f2bf(f[0]) | ((unsigned)f2bf(f[1]) << 16);
        o.y = (unsigned)f2bf(f[2]) | ((unsigned)f2bf(f[3]) << 16);
        o.z = (unsigned)f2bf(f[4]) | ((unsigned)f2bf(f[5]) << 16);
        o.w = (unsigned)f2bf(f[6]) | ((unsigned)f2bf(f[7]) << 16);
        av[i] = o;
      }
    } else {
      const unsigned short* Ap = (const unsigned short*)ga.A + (size_t)(m0 + srow) * ga.lda + k0 + sbe;
      #pragma unroll
      for (int i=0;i<4;i++) av[i] = *(const uint4*)((const char*)Ap + i*16);
    }
    const unsigned short* Bp = ga.Bt + (size_t)(n0 + srow) * ga.K + k0 + sbe;
    #pragma unroll
    for (int i=0;i<4;i++) bv[i] = *(const uint4*)((const char*)Bp + i*16);

    __syncthreads();
    #pragma unroll
    for (int i=0;i<4;i++){
      *(uint4*)((char*)lsA + swz128(srow*128 + sbe*2 + i*16)) = av[i];
      *(uint4*)((char*)lsB + swz128(srow*128 + sbe*2 + i*16)) = bv[i];
    }
    __syncthreads();
    #pragma unroll
    for (int kk=0; kk<2; kk++){
      short8 af[4], bfr[4];
      #pragma unroll
      for (int mt=0; mt<4; mt++)
        af[mt] = *(const short8*)((const char*)lsA + swz128((wm + mt*16 + col_l)*128 + kk*64 + rgrp*16));
      #pragma unroll
      for (int nt=0; nt<4; nt++)
        bfr[nt] = *(const short8*)((const char*)lsB + swz128((wn + nt*16 + col_l)*128 + kk*64 + rgrp*16));
      #pragma unroll
      for (int mt=0; mt<4; mt++)
        #pragma unroll
        for (int nt=0; nt<4; nt++)
          acc[mt][nt] = mfma16(af[mt], bfr[nt], acc[mt][nt]);
    }
  }
  #pragma unroll
  for (int nt=0; nt<4; nt++){
    int col = n0 + wn + nt*16 + col_l;
    const float* bsrc = (col < 512) ? ga.bias : ga.bias2;
    float bb = bsrc ? bsrc[col & 511] : 0.0f;
    int scol = col;
    if (ga.perm){
      int cf = col & 511;
      scol = (col & 512) + ((cf >> 7) << 7) + ((cf & 15) << 3) + ((cf >> 4) & 7);
    }
    #pragma unroll
    for (int mt=0; mt<4; mt++){
      #pragma unroll
      for (int r=0; r<4; r++){
        int row = m0 + wm + mt*16 + rgrp*4 + r;
        float v = acc[mt][nt][r] + bb;
        if (ga.act == 1) v = fast_tanh(v);
        ga.C[(size_t)row * ga.ldc + ga.coff + scol] = f2bf(v);
      }
    }
  }
}

// ---------------- phase B: tanh-RNN chunk, W_hh held in VGPRs ----------------
__global__ __launch_bounds__(256,1) void rnn_chunk(
    const unsigned short* __restrict__ rnn_in,
    const unsigned short* __restrict__ Whh_t,
    const float* __restrict__ b_hh,
    unsigned short* __restrict__ cat_d,
    float* __restrict__ dn_out,
    unsigned short* __restrict__ d_state,
    int t0, int nsteps)
{
  __shared__ __align__(16) unsigned short dls[16*256];
  const int tid = threadIdx.x, wave = tid >> 6, lane = tid & 63;
  const int col_l = lane & 15, rgrp = lane >> 4;
  const int brow0 = blockIdx.x * 16;
  const int ncol = wave * 64;

  short8 bfr[4][8];
  #pragma unroll
  for (int nt=0; nt<4; nt++){
    const unsigned short* bp = Whh_t + (size_t)(ncol + nt*16 + col_l) * 256;
    #pragma unroll
    for (int kk=0; kk<8; kk++)
      bfr[nt][kk] = *(const short8*)(bp + kk*32 + rgrp*8);
  }
  float bias[4];
  #pragma unroll
  for (int nt=0; nt<4; nt++) bias[nt] = b_hh[ncol + nt*16 + col_l];

  if (t0 == 0){
    for (int i = tid; i < 16*256; i += 256){
      int row = i >> 8, col = i & 255;
      *(unsigned short*)((char*)dls + swz512(row*512 + col*2)) = 0;
    }
  } else {
    const unsigned short* ds = d_state + (size_t)brow0 * 256;
    for (int i = tid; i < 16*256; i += 256){
      int row = i >> 8, col = i & 255;
      *(unsigned short*)((char*)dls + swz512(row*512 + col*2)) = ds[row*256 + col];
    }
  }
  __syncthreads();

  for (int tl=0; tl<nsteps; tl++){
    unsigned short rv[4][4];
    const unsigned short* rp = rnn_in + (size_t)(tl*BATCH + brow0) * 256;
    #pragma unroll
    for (int nt=0; nt<4; nt++)
      #pragma unroll
      for (int r=0; r<4; r++)
        rv[nt][r] = rp[(size_t)(rgrp*4 + r)*256 + ncol + nt*16 + col_l];

    f32x4 acc[4];
    const f32x4 z4 = {0.f,0.f,0.f,0.f};
    acc[0]=z4; acc[1]=z4; acc[2]=z4; acc[3]=z4;
    #pragma unroll
    for (int kk=0; kk<8; kk++){
      short8 af = *(const short8*)((const char*)dls + swz512((lane & 15)*512 + kk*64 + rgrp*16));
      #pragma unroll
      for (int nt=0; nt<4; nt++)
        acc[nt] = mfma16(af, bfr[nt][kk], acc[nt]);
    }
    __syncthreads();
    #pragma unroll
    for (int nt=0; nt<4; nt++){
      #pragma unroll
      for (int r=0; r<4; r++){
        float h = acc[nt][r] + bf2f(rv[nt][r]) + bias[nt];
        float d = fast_tanh(h);
        int row = rgrp*4 + r, col = ncol + nt*16 + col_l;
        unsigned short db = f2bf(d);
        *(unsigned short*)((char*)dls + swz512(row*512 + col*2)) = db;
        cat_d[(size_t)(tl*BATCH + brow0 + row)*512 + col] = db;
        if (t0 + tl == LSEQ-1) dn_out[(size_t)(brow0 + row)*256 + col] = d;
      }
    }
    __syncthreads();
  }
  unsigned short* dso = d_state + (size_t)brow0 * 256;
  for (int i = tid; i < 16*256; i += 256){
    int row = i >> 8, col = i & 255;
    dso[row*256 + col] = *(const unsigned short*)((const char*)dls + swz512(row*512 + col*2));
  }
}

// ---------------- phase D: SINGLE-CU z recurrence v2 ----------------
// 64 wgs x 4 valid batch rows; 512 threads (8 waves -> hard 256-VGPR cap).
// Budget that CLOSES: pinned weights 164 VGPR (W1 128 + mu_q 32 + ls_p tail 4),
// LDS 158208: mu_p 64K (8-way XOR) + ls_p k<448 56K (4-way XOR) + pre 16K
// (register-staged under GEMM2) + t 16.6K + z 2.3K. Working set ~85 regs.
__global__ __attribute__((amdgpu_flat_work_group_size(512, 512)))
           __attribute__((amdgpu_waves_per_eu(2, 2)))
void zrec_v2(
    const unsigned short* __restrict__ preP, const unsigned short* __restrict__ preQ, // [ns*B,1024] bf16 permuted
    const signed char* __restrict__ W1q,   // [4 mats][512 n][128 k]: f1p,f2p,f1q,f2q (natural k)
    const signed char* __restrict__ W2q,   // [3 mats][128 n][512 kperm]: mu_p, ls_p, mu_q
    const float* __restrict__ pmub, const float* __restrict__ plsb, const float* __restrict__ qmub,
    const float* __restrict__ eps,
    float* __restrict__ out_mu, float* __restrict__ out_ls, float* __restrict__ out_zn,
    signed char* __restrict__ z_state,     // [B][128] i8 persistent
    int t0, int nsteps)
{
  extern __shared__ __align__(16) char dyn[];
  char* ls_w   = dyn;            // 65536 mu_p + 57344 ls_p(kp<448)
  char* ls_pre = dyn + 122880;   // 16384: [d][4 rows][1024 elems] bf16 (permuted cols)
  char* ls_t   = dyn + 139264;   // 16640: 16 x 1040 i8 (cols permuted, d-halves)
  char* ls_z   = dyn + 155904;   // 2304: 16 x 144 i8

  const int tid = threadIdx.x, wave = tid >> 6, lane = tid & 63;
  const int col_l = lane & 15, kg = lane >> 4;
  const int brow0 = blockIdx.x * 4;        // 4 valid rows per wg
  const int d  = wave >> 2;                // 0=posterior, 1=prior
  const int wb = wave & 3;                 // GEMM1 col block (128 cols each)
  const int hc = wave * 16 + col_l;        // GEMM2 head column (0..127)

  const float DS1 = (10.0f/127.0f) * (5.0f/(127.0f*19.59591794f));
  const float DS2 = (1.0f/127.0f)  * (5.0f/(127.0f*22.62741700f));

  // ---- pinned weights ----
  i32x4 w1f[2][8][2];                      // GEMM1: f1,f2 of dblock d, cols wb*128..+127
  #pragma unroll
  for (int f=0; f<2; f++){
    int m = d*2 + f;
    #pragma unroll
    for (int j=0; j<8; j++){
      int n = wb*128 + j*16 + col_l;
      const signed char* base = W1q + ((size_t)(m*512 + n) << 7) + kg*16;
      w1f[f][j][0] = *(const i32x4*)(base);
      w1f[f][j][1] = *(const i32x4*)(base + 64);
      asm volatile("" : "+v"(w1f[f][j][0]), "+v"(w1f[f][j][1]));
    }
  }
  i32x4 wq[8];                             // mu_q full k (permuted space)
  #pragma unroll
  for (int ks=0; ks<8; ks++){
    wq[ks] = *(const i32x4*)(W2q + ((size_t)(2*128 + hc) << 9) + ks*64 + kg*16);
    asm volatile("" : "+v"(wq[ks]));
  }
  i32x4 wls;                               // ls_p kperm 448..511
  wls = *(const i32x4*)(W2q + ((size_t)(128 + hc) << 9) + 448 + kg*16);
  asm volatile("" : "+v"(wls));

  const float bp = pmub[hc], bl = plsb[hc], bq = qmub[hc];

  // ---- LDS weight fill: mu_p (full, 8-way XOR) + ls_p kp<448 (4-way XOR) ----
  for (int i = tid; i < 7680; i += 512){
    if (i < 4096){
      int n = i >> 5, kp = (i & 31) << 4;
      i32x4 v = *(const i32x4*)(W2q + ((size_t)n << 9) + kp);
      *(i32x4*)(ls_w + (n << 9) + (kp ^ ((n & 7) << 4))) = v;
    } else {
      int j = i - 4096;
      int n = j / 28, kp = (j - n*28) << 4;
      i32x4 v = *(const i32x4*)(W2q + ((size_t)(128 + n) << 9) + kp);
      *(i32x4*)(ls_w + 65536 + n*448 + (kp ^ ((n & 3) << 4))) = v;
    }
  }
  // ---- init z (rows 4-15 mirror rows 0-3; bounded garbage) ----
  if (t0 == 0){
    for (int i = tid; i < 2304; i += 512) ls_z[i] = 0;
  } else {
    for (int i = tid; i < 2048; i += 512){
      int row = i >> 7, col = i & 127;
      ls_z[row*144 + col] = z_state[(size_t)(brow0 + (row & 3))*128 + col];
    }
  }
  // ---- stage pre[0]: threads 0-255 -> preP rows, 256-511 -> preQ rows ----
  {
    const unsigned short* sb = ((tid >> 8) ? preQ : preP)
                             + ((size_t)t0*0 + (size_t)(0*BATCH) + brow0)*1024 + (size_t)(tid & 255)*16;
    i32x4 s0 = *(const i32x4*)(sb);
    i32x4 s1 = *(const i32x4*)(sb + 8);
    char* dst = ls_pre + (tid >> 8)*8192 + (size_t)(tid & 255)*32;
    *(i32x4*)dst = s0; *(i32x4*)(dst + 16) = s1;
  }
  __syncthreads();

  for (int tl = 0; tl < nsteps; ++tl){
    // eps for this step (broadcast rows 0-3; used in epilogue)
    float er[4];
    #pragma unroll
    for (int r=0; r<4; r++)
      er[r] = eps[((size_t)(t0 + tl)*BATCH + brow0 + r)*STATE + hc];

    // ---- GEMM1: z @ W1 -> t (activation), pre from LDS broadcasts ----
    i32x4 zf0 = *(const i32x4*)(ls_z + col_l*144 + kg*16);
    i32x4 zf1 = *(const i32x4*)(ls_z + col_l*144 + 64 + kg*16);
    const int pbase = d*8192 + wb*256 + col_l*16;

    #pragma unroll
    for (int q = 0; q < 4; q++){
      unsigned pv[2][4];   // [f][r] : 2 bf16 (j = q*2, q*2+1)
      #pragma unroll
      for (int f=0; f<2; f++)
        #pragma unroll
        for (int r=0; r<4; r++)
          pv[f][r] = *(const unsigned*)(ls_pre + pbase + r*2048 + f*1024 + q*4);

      i32x4 acc[2][2];
      const i32x4 zz = {0,0,0,0};
      acc[0][0]=zz; acc[0][1]=zz; acc[1][0]=zz; acc[1][1]=zz;
      #pragma unroll
      for (int f=0; f<2; f++)
        #pragma unroll
        for (int nt=0; nt<2; nt++){
          acc[f][nt] = mfma_i8(zf0, w1f[f][q*2+nt][0], acc[f][nt]);
          acc[f][nt] = mfma_i8(zf1, w1f[f][q*2+nt][1], acc[f][nt]);
        }
      #pragma unroll
      for (int r=0; r<4; r++){
        int tb[2];
        #pragma unroll
        for (int nt=0; nt<2; nt++){
          unsigned wa = pv[0][r], wbv = pv[1][r];
          unsigned short ua = nt ? (unsigned short)(wa >> 16) : (unsigned short)(wa & 0xffff);
          unsigned short ub = nt ? (unsigned short)(wbv >> 16) : (unsigned short)(wbv & 0xffff);
          float h1 = (float)acc[0][nt][r] * DS1 + bf2f(ua);
          float h2 = (float)acc[1][nt][r] * DS1 + bf2f(ub);
          float tv = fast_tanh(h1) * fast_sig(h2);
          tb[nt] = (int)rintf(tv * 127.0f) & 255;
        }
        *(unsigned short*)(ls_t + (kg*4 + r)*1040 + d*512 + wb*128 + col_l*8 + q*2)
            = (unsigned short)(tb[0] | (tb[1] << 8));
      }
    }
    __syncthreads();   // (A) t visible, pre consumed

    // ---- issue next-step pre stage loads (consumed after GEMM2) ----
    int nx = (tl+1 < nsteps) ? tl+1 : tl;
    const unsigned short* sb = ((tid >> 8) ? preQ : preP)
                             + ((size_t)(nx*BATCH) + brow0)*1024 + (size_t)(tid & 255)*16;
    i32x4 s0 = *(const i32x4*)(sb);
    i32x4 s1 = *(const i32x4*)(sb + 8);

    // ---- GEMM2: heads (K=512 permuted), B: mu_p LDS / ls_p LDS+VGPR / mu_q VGPR ----
    i32x4 amp = {0,0,0,0}, als = {0,0,0,0}, amq = {0,0,0,0};
    #pragma unroll
    for (int ks=0; ks<8; ks++){
      i32x4 Ap = *(const i32x4*)(ls_t + col_l*1040 + ks*64 + kg*16);
      i32x4 Aq = *(const i32x4*)(ls_t + col_l*1040 + 512 + ks*64 + kg*16);
      int kp = ks*64 + kg*16;
      i32x4 Bp = *(const i32x4*)(ls_w + (hc << 9) + (kp ^ ((hc & 7) << 4)));
      amp = mfma_i8(Ap, Bp, amp);
      i32x4 Bl;
      if (ks < 7) Bl = *(const i32x4*)(ls_w + 65536 + hc*448 + (kp ^ ((hc & 3) << 4)));
      else        Bl = wls;
      als = mfma_i8(Ap, Bl, als);
      amq = mfma_i8(Aq, wq[ks], amq);
    }
    // ---- epilogue: mu, ls, z (stores only kg==0 -> rows 0-3 valid) ----
    size_t growr = (size_t)(t0 + tl)*BATCH + brow0 + kg*4;
    #pragma unroll
    for (int r=0; r<4; r++){
      float mu = ((float)amq[r] * DS2 + bq) + ((float)amp[r] * DS2 + bp);
      float ls = (float)als[r] * DS2 + bl;
      float z  = mu + __expf(0.5f * ls) * er[r];
      int row = kg*4 + r;
      if (kg == 0){
        out_mu[(growr + r)*STATE + hc] = mu;
        out_ls[(growr + r)*STATE + hc] = ls;
        if (t0 + tl == LSEQ-1) out_zn[(size_t)(brow0 + row)*STATE + hc] = z;
      }
      float zq = fminf(fmaxf(rintf(z * 12.7f), -127.0f), 127.0f);
      ls_z[row*144 + hc] = (signed char)(int)zq;
    }
    // ---- write staged pre ----
    {
      char* dst = ls_pre + (tid >> 8)*8192 + (size_t)(tid & 255)*32;
      *(i32x4*)dst = s0; *(i32x4*)(dst + 16) = s1;
    }
    __syncthreads();   // (B) z + staged pre visible
  }

  // persist z state (4 valid rows)
  if (tid < 512){
    int row = tid >> 7, col = tid & 127;
    if (row < 4)
      z_state[(size_t)(brow0 + row)*128 + col] = ls_z[row*144 + col];
  }
}

// ---------------- host launcher ----------------
extern "C" void kernel_launch(void* const* d_in, const int* in_sizes, int n_in,
                              void* d_out, int out_size, void* d_ws, size_t ws_size,
                              hipStream_t stream)
{
  const float* ext = (const float*)d_in[0];
  const float* obs = (const float*)d_in[1];
  const float* eps = (const float*)d_in[2];
  const float* Wu  = (const float*)d_in[3];
  const float* bu  = (const float*)d_in[4];
  const float* Wx  = (const float*)d_in[5];
  const float* bx  = (const float*)d_in[6];
  const float* W_ih= (const float*)d_in[7];
  const float* b_ih= (const float*)d_in[8];
  const float* W_hh= (const float*)d_in[9];
  const float* b_hh= (const float*)d_in[10];
  const float* Wa1 = (const float*)d_in[11];
  const float* ba1 = (const float*)d_in[12];
  const float* Wa2 = (const float*)d_in[13];
  const float* ba2 = (const float*)d_in[14];
  const float* pf1W= (const float*)d_in[15]; const float* pf1b = (const float*)d_in[16];
  const float* pf2W= (const float*)d_in[17]; const float* pf2b = (const float*)d_in[18];
  const float* pmuW= (const float*)d_in[19]; const float* pmub = (const float*)d_in[20];
  const float* plsW= (const float*)d_in[21]; const float* plsb = (const float*)d_in[22];
  const float* qf1W= (const float*)d_in[23]; const float* qf1b = (const float*)d_in[24];
  const float* qf2W= (const float*)d_in[25]; const float* qf2b = (const float*)d_in[26];
  const float* qmuW= (const float*)d_in[27]; const float* qmub = (const float*)d_in[28];

  int NC = 0;
  const int cands[7] = {1,2,4,8,16,32,64};
  size_t rows = 0;
  for (int ci=0; ci<7; ci++){
    size_t r = (size_t)(LSEQ/cands[ci])*BATCH;
    size_t elems = 1600000 + r*3072;
    if (elems * 2 <= ws_size){ NC = cands[ci]; rows = r; break; }
  }
  if (!NC) return;
  const int nsteps = LSEQ/NC;
  const int gx = (int)(rows/128);

  unsigned short* ws = (unsigned short*)d_ws;
  size_t off = 0;
  auto alloc = [&](size_t elems){
    unsigned short* p = ws + off;
    off += (elems + 127) & ~(size_t)127;
    return p;
  };

  unsigned short* Wu_t  = alloc(64*256);
  unsigned short* Wx_t  = alloc(64*256);
  unsigned short* Wih_t = alloc(256*256);
  unsigned short* Whh_t = alloc(256*256);
  unsigned short* Wa1_t = alloc(512*256);
  unsigned short* Wa2_t = alloc(256*256);
  unsigned short* fAp   = alloc(1024*256);
  unsigned short* fAq   = alloc(1024*256);
  signed char*    W1q   = (signed char*)alloc(131072);
  signed char*    W2q   = (signed char*)alloc(98304);
  unsigned short* d_state = alloc(256*256);
  signed char*    z_state = (signed char*)alloc(16384);
  unsigned short* bufA  = alloc(rows*256);
  unsigned short* bufB  = alloc(rows*256);
  unsigned short* bufC  = alloc(rows*512);
  unsigned short* preP  = alloc(rows*1024);
  unsigned short* preQ  = alloc(rows*1024);
  if (off * sizeof(unsigned short) > ws_size) return;

  float* out_mu = (float*)d_out;
  float* out_ls = out_mu + (size_t)LSEQ*BATCH*STATE;
  float* out_dn = out_ls + (size_t)LSEQ*BATCH*STATE;
  float* out_zn = out_dn + (size_t)BATCH*KDIM;

  WDescs wd;
  int wi = 0;
  auto add = [&](const float* s, unsigned short* dst, int Kk, int Nn, int ld, int ro, int co){
    wd.d[wi].src = s; wd.d[wi].dst = dst; wd.d[wi].K = Kk; wd.d[wi].N = Nn;
    wd.d[wi].ld = ld; wd.d[wi].rowoff = ro; wd.d[wi].coloff = co; wi++;
  };
  add(Wu,   Wu_t,  64, 256, 256, 0, 0);
  add(Wx,   Wx_t,  64, 256, 256, 0, 0);
  add(W_ih, Wih_t, 256, 256, 256, 0, 0);
  add(W_hh, Whh_t, 256, 256, 256, 0, 0);
  add(Wa1,  Wa1_t, 512, 256, 256, 0, 0);
  add(Wa2,  Wa2_t, 256, 256, 256, 0, 0);
  add(pf1W, fAp,            256, 512, 512, 128, 0);
  add(pf2W, fAp + 512*256,  256, 512, 512, 128, 0);
  add(qf1W, fAq,            256, 512, 512, 128, 0);
  add(qf2W, fAq + 512*256,  256, 512, 512, 128, 0);

  const float INV1 = 127.0f * 19.59591794f / 5.0f;
  const float INV2 = 127.0f * 22.62741700f / 5.0f;
  QDescs qd;
  auto addq = [&](int i, const float* s, signed char* dst, int Kk, int Nn, int ld, float is, int kp){
    qd.d[i].src = s; qd.d[i].dst = dst; qd.d[i].K = Kk; qd.d[i].N = Nn;
    qd.d[i].ld = ld; qd.d[i].inv_s = is; qd.d[i].kperm = kp;
  };
  addq(0, pf1W, W1q + 0*65536, 128, 512, 512, INV1, 0);
  addq(1, pf2W, W1q + 1*65536, 128, 512, 512, INV1, 0);
  addq(2, qf1W, W1q + 2*65536, 128, 512, 512, INV1, 0);
  addq(3, qf2W, W1q + 3*65536, 128, 512, 512, INV1, 0);
  addq(4, pmuW, W2q + 0*65536, 512, 128, 128, INV2, 1);
  addq(5, plsW, W2q + 1*65536, 512, 128, 128, INV2, 1);
  addq(6, qmuW, W2q + 2*65536, 512, 128, 128, INV2, 1);

  convert_weights<<<dim3(512,10), 256, 0, stream>>>(wd);
  convert_q8<<<dim3(256,7), 256, 0, stream>>>(qd);

  hipFuncSetAttribute((const void*)zrec_v2,
                      hipFuncAttributeMaxDynamicSharedMemorySize, 158208);

  for (int c=0; c<NC; ++c){
    const int t0 = c * nsteps;
    const size_t row0 = (size_t)t0 * BATCH;

    GArgs e{};
    e.g[0] = GArg{ext + row0*64, Wu_t, bu, bu, bufA, 64, 256, 0,   64, 1, 1, 0};
    e.g[1] = GArg{obs + row0*64, Wx_t, bx, bx, bufC, 64, 512, 256, 64, 1, 1, 0};
    gemm_multi<<<dim3(gx,2,2), 256, 0, stream>>>(e);

    GArgs rn{};
    rn.g[0] = GArg{bufA, Wih_t, b_ih, b_ih, bufB, 256, 256, 0, 256, 0, 0, 0};
    gemm_multi<<<dim3(gx,2,1), 256, 0, stream>>>(rn);

    rnn_chunk<<<16, 256, 0, stream>>>(bufB, Whh_t, b_hh, bufC, out_dn, d_state, t0, nsteps);

    GArgs a1{};
    a1.g[0] = GArg{bufC, Wa1_t, ba1, ba1, bufA, 512, 256, 0, 512, 1, 0, 0};
    gemm_multi<<<dim3(gx,2,1), 256, 0, stream>>>(a1);

    GArgs a2{};
    a2.g[0] = GArg{bufA, Wa2_t, ba2, ba2, bufB, 256, 256, 0, 256, 0, 0, 0};
    gemm_multi<<<dim3(gx,2,1), 256, 0, stream>>>(a2);

    GArgs pr{};
    pr.g[0] = GArg{bufB, fAp, pf1b, pf2b, preP, 256, 1024, 0, 256, 0, 0, 1};
    pr.g[1] = GArg{bufC, fAq, qf1b, qf2b, preQ, 512, 1024, 0, 256, 0, 0, 1};
    gemm_multi<<<dim3(gx,8,2), 256, 0, stream>>>(pr);

    zrec_v2<<<64, 512, 158208, stream>>>(preP, preQ, W1q, W2q,
                                         pmub, plsb, qmub, eps, out_mu, out_ls, out_zn,
                                         z_state, t0, nsteps);
  }
}

// Round 12
// 3621.658 us; speedup vs baseline: 1.8146x; 1.4831x over previous
//
#include <hip/hip_runtime.h>

#define LSEQ 512
#define BATCH 256
#define KDIM 256
#define STATE 128

using f32x4  = __attribute__((ext_vector_type(4))) float;
using short8 = __attribute__((ext_vector_type(8))) short;
using u32x2  = __attribute__((ext_vector_type(2))) unsigned int;
using u32x4  = __attribute__((ext_vector_type(4))) unsigned int;

__device__ __forceinline__ float bf2f(unsigned short u){
  return __uint_as_float(((unsigned int)u) << 16);
}
__device__ __forceinline__ unsigned short f2bf(float f){
  unsigned int u = __float_as_uint(f);
  u += 0x7FFFu + ((u >> 16) & 1u);   // RNE
  return (unsigned short)(u >> 16);
}
__device__ __forceinline__ float fast_tanh(float x){
  float ax = fabsf(x);
  float e  = __expf(2.0f * ax);
  float t  = 1.0f - 2.0f / (e + 1.0f);
  return copysignf(t, x);
}
__device__ __forceinline__ float fast_sig(float x){
  return 1.0f / (1.0f + __expf(-x));
}
__device__ __forceinline__ f32x4 mfma16(short8 a, short8 b, f32x4 c){
  return __builtin_amdgcn_mfma_f32_16x16x32_bf16(a, b, c, 0, 0, 0);
}

__device__ __forceinline__ int swz128 (int b){ return b ^ ((((b >> 7) & 7) << 4)); }
__device__ __forceinline__ int swz256 (int b){ return b ^ ((((b >> 8) & 7) << 4)); }
__device__ __forceinline__ int swz512 (int b){ return b ^ ((((b >> 9) & 7) << 4)); }

// ---- Infinity-Cache-scope accessors (sc0 sc1): coherent on any XCD placement.
__device__ __forceinline__ void st_b128_ic(void* p, u32x4 v){
  asm volatile("global_store_dwordx4 %0, %1, off sc0 sc1" :: "v"(p), "v"(v) : "memory");
}
__device__ __forceinline__ void st_b64_ic(void* p, u32x2 v){
  asm volatile("global_store_dwordx2 %0, %1, off sc0 sc1" :: "v"(p), "v"(v) : "memory");
}
#define LD2_IC(dst, p) asm volatile("global_load_dwordx2 %0, %1, off sc0 sc1" : "=v"(dst) : "v"(p) : "memory")

__device__ __forceinline__ f32x4 cvt4(u32x2 q){
  f32x4 r;
  r[0] = __uint_as_float(q[0] << 16);
  r[1] = __uint_as_float(q[0] & 0xFFFF0000u);
  r[2] = __uint_as_float(q[1] << 16);
  r[3] = __uint_as_float(q[1] & 0xFFFF0000u);
  return r;
}

// ---------------- weight convert: f32 src[rowoff+k][coloff+n] -> bf16 dst[n*K+k] ----------------
struct WDesc { const float* src; unsigned short* dst; int K, N, ld, rowoff, coloff; };
struct WDescs { WDesc d[24]; };

__global__ __launch_bounds__(256,4) void convert_weights(WDescs ds){
  WDesc w = ds.d[blockIdx.y];
  int total = w.K * w.N;
  int idx = blockIdx.x * 256 + threadIdx.x;
  if (idx < total){
    int n = idx / w.K;
    int k = idx - n * w.K;
    w.dst[idx] = f2bf(w.src[(size_t)(w.rowoff + k) * w.ld + w.coloff + n]);
  }
}

__global__ __launch_bounds__(256,1) void init_flags(int* flags){
  flags[blockIdx.x * 256 + threadIdx.x] = 0;
}

// ---------------- gemm_multi: reg-staged path (f32 A inputs; K=64 embeddings) ----------------
struct GArg {
  const void* A; const unsigned short* Bt; const float* bias; const float* bias2;
  unsigned short* C; int lda, ldc, coff, K, act, a_f32;
};
struct GArgs { GArg g[4]; };

__global__ __launch_bounds__(256,2) void gemm_multi(GArgs args){
  GArg ga = args.g[blockIdx.z];
  __shared__ __align__(16) unsigned short lsA[128*64];
  __shared__ __align__(16) unsigned short lsB[128*64];
  const int tid  = threadIdx.x;
  const int wave = tid >> 6, lane = tid & 63;
  const int col_l = lane & 15, rgrp = lane >> 4;
  const int m0 = blockIdx.x * 128, n0 = blockIdx.y * 128;
  const int wm = (wave >> 1) * 64, wn = (wave & 1) * 64;

  f32x4 acc[4][4];
  const f32x4 z4 = {0.f,0.f,0.f,0.f};
  #pragma unroll
  for (int i=0;i<4;i++){ acc[i][0]=z4; acc[i][1]=z4; acc[i][2]=z4; acc[i][3]=z4; }

  const int srow = tid >> 1;
  const int sbe  = (tid & 1) * 32;

  for (int k0 = 0; k0 < ga.K; k0 += 64){
    uint4 av[4], bv[4];
    if (ga.a_f32){
      const float* Ap = (const float*)ga.A + (size_t)(m0 + srow) * ga.lda + k0 + sbe;
      uint4 fv[8];
      #pragma unroll
      for (int i=0;i<8;i++) fv[i] = *(const uint4*)((const char*)Ap + i*16);
      #pragma unroll
      for (int i=0;i<4;i++){
        const float* f = (const float*)&fv[i*2];
        uint4 o;
        o.x = (unsigned)f2bf(f[0]) | ((unsigned)f2bf(f[1]) << 16);
        o.y = (unsigned)f2bf(f[2]) | ((unsigned)f2bf(f[3]) << 16);
        o.z = (unsigned)f2bf(f[4]) | ((unsigned)f2bf(f[5]) << 16);
        o.w = (unsigned)f2bf(f[6]) | ((unsigned)f2bf(f[7]) << 16);
        av[i] = o;
      }
    } else {
      const unsigned short* Ap = (const unsigned short*)ga.A + (size_t)(m0 + srow) * ga.lda + k0 + sbe;
      #pragma unroll
      for (int i=0;i<4;i++) av[i] = *(const uint4*)((const char*)Ap + i*16);
    }
    const unsigned short* Bp = ga.Bt + (size_t)(n0 + srow) * ga.K + k0 + sbe;
    #pragma unroll
    for (int i=0;i<4;i++) bv[i] = *(const uint4*)((const char*)Bp + i*16);

    __syncthreads();
    #pragma unroll
    for (int i=0;i<4;i++){
      *(uint4*)((char*)lsA + swz128(srow*128 + sbe*2 + i*16)) = av[i];
      *(uint4*)((char*)lsB + swz128(srow*128 + sbe*2 + i*16)) = bv[i];
    }
    __syncthreads();
    #pragma unroll
    for (int kk=0; kk<2; kk++){
      short8 af[4], bfr[4];
      #pragma unroll
      for (int mt=0; mt<4; mt++)
        af[mt] = *(const short8*)((const char*)lsA + swz128((wm + mt*16 + col_l)*128 + kk*64 + rgrp*16));
      #pragma unroll
      for (int nt=0; nt<4; nt++)
        bfr[nt] = *(const short8*)((const char*)lsB + swz128((wn + nt*16 + col_l)*128 + kk*64 + rgrp*16));
      #pragma unroll
      for (int mt=0; mt<4; mt++)
        #pragma unroll
        for (int nt=0; nt<4; nt++)
          acc[mt][nt] = mfma16(af[mt], bfr[nt], acc[mt][nt]);
    }
  }
  #pragma unroll
  for (int nt=0; nt<4; nt++){
    int col = n0 + wn + nt*16 + col_l;
    const float* bsrc = (col < 512) ? ga.bias : ga.bias2;
    float bb = bsrc ? bsrc[col & 511] : 0.0f;
    #pragma unroll
    for (int mt=0; mt<4; mt++){
      #pragma unroll
      for (int r=0; r<4; r++){
        int row = m0 + wm + mt*16 + rgrp*4 + r;
        float v = acc[mt][nt][r] + bb;
        if (ga.act == 1) v = fast_tanh(v);
        ga.C[(size_t)row * ga.ldc + ga.coff + col] = f2bf(v);
      }
    }
  }
}

// ---------------- gemm_glds: bf16 GEMM with global_load_lds(16B) staging ----------------
// Double-buffered 64KB LDS; pre-swizzled global source so linear glds writes land
// where the swz128 reads expect (both-sides-or-neither). 2 barriers + vmcnt(8)/iter.
struct GArg2 {
  const unsigned short* A; const unsigned short* Bt; const float* bias; const float* bias2;
  unsigned short* C; int lda, ldc, coff, K, act;
};
struct GArgs2 { GArg2 g[2]; };

__global__ __launch_bounds__(256,2) void gemm_glds(GArgs2 args){
  GArg2 ga = args.g[blockIdx.z];
  __shared__ __align__(16) unsigned short ls[4][128*64];  // A0,B0,A1,B1
  const int tid  = threadIdx.x;
  const int wave = tid >> 6, lane = tid & 63;
  const int col_l = lane & 15, rgrp = lane >> 4;
  const int m0 = blockIdx.x * 128, n0 = blockIdx.y * 128;
  const int wm = (wave >> 1) * 64, wn = (wave & 1) * 64;

  // stage geometry: wave covers rows [wave*32, wave*32+32) in 4 chunks of 8 rows;
  // lane l: row = chunk*8 + (l>>3), source col = ((l&7)^(l>>3))*8 elems (pre-swizzle)
  const int lrow = lane >> 3;
  const int scol = (((lane & 7) ^ lrow) << 3);

  auto STAGE = [&](int k0, int buf){
    #pragma unroll
    for (int c = 0; c < 4; c++){
      int srow = wave*32 + c*8 + lrow;
      const unsigned short* pa = ga.A  + (size_t)(m0 + srow) * ga.lda + k0 + scol;
      const unsigned short* pb = ga.Bt + (size_t)(n0 + srow) * ga.K  + k0 + scol;
      __builtin_amdgcn_global_load_lds(
          (const __attribute__((address_space(1))) unsigned int*)pa,
          (__attribute__((address_space(3))) unsigned int*)((char*)&ls[buf*2][0]   + wave*4096 + c*1024),
          16, 0, 0);
      __builtin_amdgcn_global_load_lds(
          (const __attribute__((address_space(1))) unsigned int*)pb,
          (__attribute__((address_space(3))) unsigned int*)((char*)&ls[buf*2+1][0] + wave*4096 + c*1024),
          16, 0, 0);
    }
  };

  f32x4 acc[4][4];
  const f32x4 z4 = {0.f,0.f,0.f,0.f};
  #pragma unroll
  for (int i=0;i<4;i++){ acc[i][0]=z4; acc[i][1]=z4; acc[i][2]=z4; acc[i][3]=z4; }

  const int niter = ga.K >> 6;
  STAGE(0, 0);

  for (int i = 0; i < niter; i++){
    if (i + 1 < niter){
      STAGE((i+1)*64, (i+1) & 1);
      asm volatile("s_waitcnt vmcnt(8)" ::: "memory");   // current buf's 8 landed
    } else {
      asm volatile("s_waitcnt vmcnt(0)" ::: "memory");
    }
    __syncthreads();
    const char* la = (const char*)&ls[(i&1)*2][0];
    const char* lb = (const char*)&ls[(i&1)*2+1][0];
    #pragma unroll
    for (int kk=0; kk<2; kk++){
      short8 af[4], bfr[4];
      #pragma unroll
      for (int mt=0; mt<4; mt++)
        af[mt] = *(const short8*)(la + swz128((wm + mt*16 + col_l)*128 + kk*64 + rgrp*16));
      #pragma unroll
      for (int nt=0; nt<4; nt++)
        bfr[nt] = *(const short8*)(lb + swz128((wn + nt*16 + col_l)*128 + kk*64 + rgrp*16));
      #pragma unroll
      for (int mt=0; mt<4; mt++)
        #pragma unroll
        for (int nt=0; nt<4; nt++)
          acc[mt][nt] = mfma16(af[mt], bfr[nt], acc[mt][nt]);
    }
    __syncthreads();   // reads done; buf may be overwritten by stage i+2
  }

  #pragma unroll
  for (int nt=0; nt<4; nt++){
    int col = n0 + wn + nt*16 + col_l;
    const float* bsrc = (col < 512) ? ga.bias : ga.bias2;
    float bb = bsrc ? bsrc[col & 511] : 0.0f;
    #pragma unroll
    for (int mt=0; mt<4; mt++){
      #pragma unroll
      for (int r=0; r<4; r++){
        int row = m0 + wm + mt*16 + rgrp*4 + r;
        float v = acc[mt][nt][r] + bb;
        if (ga.act == 1) v = fast_tanh(v);
        ga.C[(size_t)row * ga.ldc + ga.coff + col] = f2bf(v);
      }
    }
  }
}

// ---------------- phase B: tanh-RNN chunk, W_hh held in VGPRs ----------------
__global__ __launch_bounds__(256,1) void rnn_chunk(
    const unsigned short* __restrict__ rnn_in,
    const unsigned short* __restrict__ Whh_t,
    const float* __restrict__ b_hh,
    unsigned short* __restrict__ cat_d,
    float* __restrict__ dn_out,
    unsigned short* __restrict__ d_state,
    int t0, int nsteps)
{
  __shared__ __align__(16) unsigned short dls[16*256];
  const int tid = threadIdx.x, wave = tid >> 6, lane = tid & 63;
  const int col_l = lane & 15, rgrp = lane >> 4;
  const int brow0 = blockIdx.x * 16;
  const int ncol = wave * 64;

  short8 bfr[4][8];
  #pragma unroll
  for (int nt=0; nt<4; nt++){
    const unsigned short* bp = Whh_t + (size_t)(ncol + nt*16 + col_l) * 256;
    #pragma unroll
    for (int kk=0; kk<8; kk++)
      bfr[nt][kk] = *(const short8*)(bp + kk*32 + rgrp*8);
  }
  float bias[4];
  #pragma unroll
  for (int nt=0; nt<4; nt++) bias[nt] = b_hh[ncol + nt*16 + col_l];

  if (t0 == 0){
    for (int i = tid; i < 16*256; i += 256){
      int row = i >> 8, col = i & 255;
      *(unsigned short*)((char*)dls + swz512(row*512 + col*2)) = 0;
    }
  } else {
    const unsigned short* ds = d_state + (size_t)brow0 * 256;
    for (int i = tid; i < 16*256; i += 256){
      int row = i >> 8, col = i & 255;
      *(unsigned short*)((char*)dls + swz512(row*512 + col*2)) = ds[row*256 + col];
    }
  }
  __syncthreads();

  for (int tl=0; tl<nsteps; tl++){
    unsigned short rv[4][4];
    const unsigned short* rp = rnn_in + (size_t)(tl*BATCH + brow0) * 256;
    #pragma unroll
    for (int nt=0; nt<4; nt++)
      #pragma unroll
      for (int r=0; r<4; r++)
        rv[nt][r] = rp[(size_t)(rgrp*4 + r)*256 + ncol + nt*16 + col_l];

    f32x4 acc[4];
    const f32x4 z4 = {0.f,0.f,0.f,0.f};
    acc[0]=z4; acc[1]=z4; acc[2]=z4; acc[3]=z4;
    #pragma unroll
    for (int kk=0; kk<8; kk++){
      short8 af = *(const short8*)((const char*)dls + swz512((lane & 15)*512 + kk*64 + rgrp*16));
      #pragma unroll
      for (int nt=0; nt<4; nt++)
        acc[nt] = mfma16(af, bfr[nt][kk], acc[nt]);
    }
    __syncthreads();
    #pragma unroll
    for (int nt=0; nt<4; nt++){
      #pragma unroll
      for (int r=0; r<4; r++){
        float h = acc[nt][r] + bf2f(rv[nt][r]) + bias[nt];
        float d = fast_tanh(h);
        int row = rgrp*4 + r, col = ncol + nt*16 + col_l;
        unsigned short db = f2bf(d);
        *(unsigned short*)((char*)dls + swz512(row*512 + col*2)) = db;
        cat_d[(size_t)(tl*BATCH + brow0 + row)*512 + col] = db;
        if (t0 + tl == LSEQ-1) dn_out[(size_t)(brow0 + row)*256 + col] = d;
      }
    }
    __syncthreads();
  }
  unsigned short* dso = d_state + (size_t)brow0 * 256;
  for (int i = tid; i < 16*256; i += 256){
    int row = i >> 8, col = i & 255;
    dso[row*256 + col] = *(const unsigned short*)((const char*)dls + swz512(row*512 + col*2));
  }
}

// ---------------- phase D: weight-stationary z recurrence, IC mailbox (r6, proven 1089us) ----------------
__global__ __launch_bounds__(512,1) void zrec_mb(
    const unsigned short* __restrict__ preP, const unsigned short* __restrict__ preQ, // [ns*B,1024]
    const unsigned short* __restrict__ Wzz,  // [4 roles][2 mats][256 n][128 k]
    const unsigned short* __restrict__ W2,   // [4 roles][2 mats][128 n][256 k]
    const float* __restrict__ pmub, const float* __restrict__ plsb, const float* __restrict__ qmub,
    const float* __restrict__ eps,
    float* __restrict__ out_mu, float* __restrict__ out_ls, float* __restrict__ out_zn,
    unsigned short* __restrict__ z_state,
    unsigned short* __restrict__ mb, int* __restrict__ flags,
    int t0, int nsteps, int fbase)
{
  __shared__ __align__(16) unsigned short zls[16*128];
  __shared__ __align__(16) unsigned short tls[16*256];
  const int tid = threadIdx.x, wave = tid >> 6, lane = tid & 63;
  const int col_l = lane & 15, rgrp = lane >> 4;
  const int bid = blockIdx.x;
  const int c   = (bid >> 3) & 3;
  const int g   = (bid & 7) + ((bid >> 5) << 3);
  const int brow0 = g * 16;
  const int NT2 = (c < 2) ? 2 : 1;

  const unsigned short* pre = (c < 2) ? preP : preQ;
  const int cb = (c & 1) * 256;

  short8 w1[2][2][4];
  {
    const unsigned short* wz = Wzz + (size_t)c * 65536;
    #pragma unroll
    for (int m=0; m<2; m++)
      #pragma unroll
      for (int nt=0; nt<2; nt++){
        int n = wave*32 + nt*16 + col_l;
        #pragma unroll
        for (int kk=0; kk<4; kk++)
          w1[m][nt][kk] = *(const short8*)(wz + (size_t)(m*256 + n)*128 + kk*32 + rgrp*8);
      }
  }
  short8 w2r[2][8];
  {
    const unsigned short* wp = W2 + (size_t)c * 65536;
    #pragma unroll
    for (int nt=0; nt<2; nt++){
      if (nt < NT2){
        int ccol = wave*(16*((c<2)?2:1)) + nt*16;
        int mat = (c < 2) ? (ccol >> 7) : 0;
        int n   = (ccol & 127) + col_l;
        #pragma unroll
        for (int kk=0; kk<8; kk++)
          w2r[nt][kk] = *(const short8*)(wp + (size_t)(mat*128 + n)*256 + kk*32 + rgrp*8);
      }
    }
  }
  int* const myflag = flags + (g*4 + c)*32;

  if (t0 == 0){
    for (int i = tid; i < 16*128; i += 512){
      int row = i >> 7, col = i & 127;
      *(unsigned short*)((char*)zls + swz256(row*256 + col*2)) = 0;
    }
  } else {
    const unsigned short* zs = z_state + (size_t)brow0 * 128;
    for (int i = tid; i < 16*128; i += 512){
      int row = i >> 7, col = i & 127;
      *(unsigned short*)((char*)zls + swz256(row*256 + col*2)) = zs[row*128 + col];
    }
  }
  __syncthreads();

  auto LD_PRE = [&](int tl, unsigned short (&pa_)[2][4], unsigned short (&pb_)[2][4]){
    const unsigned short* bA = pre + ((size_t)tl*BATCH + brow0)*1024 + cb;
    #pragma unroll
    for (int nt=0; nt<2; nt++)
      #pragma unroll
      for (int r=0; r<4; r++){
        int row = rgrp*4 + r, col = wave*32 + nt*16 + col_l;
        pa_[nt][r] = bA[(size_t)row*1024 + col];
        pb_[nt][r] = bA[(size_t)row*1024 + 512 + col];
      }
  };

  const int rrow = tid >> 5;
  const int rc0  = (tid & 31) * 4;
  const f32x4 bp4 = *(const f32x4*)(pmub + rc0);
  const f32x4 bl4 = *(const f32x4*)(plsb + rc0);
  const f32x4 bq4 = *(const f32x4*)(qmub + rc0);

  unsigned short pa0[2][4], pb0[2][4], pa1[2][4], pb1[2][4];
  LD_PRE(0, pa0, pb0);

  const f32x4 z4 = {0.f,0.f,0.f,0.f};
  for (int tl=0; tl<nsteps; ++tl){
    size_t growr = (size_t)(t0+tl)*BATCH + brow0 + rrow;
    f32x4 er = *(const f32x4*)(eps + growr*STATE + rc0);
    int nx = (tl+1 < nsteps) ? tl+1 : tl;
    LD_PRE(nx, pa1, pb1);

    short8 af1[4];
    #pragma unroll
    for (int kk=0; kk<4; kk++)
      af1[kk] = *(const short8*)((const char*)zls + swz256((lane & 15)*256 + kk*64 + rgrp*16));
    f32x4 a1[2][2];
    a1[0][0]=z4; a1[0][1]=z4; a1[1][0]=z4; a1[1][1]=z4;
    #pragma unroll
    for (int kk=0; kk<4; kk++)
      #pragma unroll
      for (int m=0; m<2; m++)
        #pragma unroll
        for (int nt=0; nt<2; nt++)
          a1[m][nt] = mfma16(af1[kk], w1[m][nt][kk], a1[m][nt]);

    #pragma unroll
    for (int nt=0; nt<2; nt++)
      #pragma unroll
      for (int r=0; r<4; r++){
        float h1 = a1[0][nt][r] + bf2f(pa0[nt][r]);
        float h2 = a1[1][nt][r] + bf2f(pb0[nt][r]);
        float tv = fast_tanh(h1) * fast_sig(h2);
        int row = rgrp*4 + r, tcol = wave*32 + nt*16 + col_l;
        *(unsigned short*)((char*)tls + swz512(row*512 + tcol*2)) = f2bf(tv);
      }
    __syncthreads();

    f32x4 a2[2];
    a2[0]=z4; a2[1]=z4;
    #pragma unroll
    for (int kk=0; kk<8; kk++){
      short8 af2 = *(const short8*)((const char*)tls + swz512((lane & 15)*512 + kk*64 + rgrp*16));
      #pragma unroll
      for (int nt=0; nt<2; nt++)
        if (nt < NT2) a2[nt] = mfma16(af2, w2r[nt][kk], a2[nt]);
    }
    __syncthreads();   // tls reads done -> reuse as publish bounce (linear bf16)

    if (c < 2){
      #pragma unroll
      for (int nt=0; nt<2; nt++)
        #pragma unroll
        for (int r=0; r<4; r++)
          tls[(rgrp*4 + r)*256 + wave*32 + nt*16 + col_l] = f2bf(a2[nt][r]);
    } else {
      #pragma unroll
      for (int r=0; r<4; r++)
        tls[(rgrp*4 + r)*128 + wave*16 + col_l] = f2bf(a2[0][r]);
    }
    __syncthreads();

    unsigned short* slot = mb + (size_t)((g*2 + (tl & 1))*4 + c)*4096;
    if (c < 2){
      u32x4 v = *(const u32x4*)((const char*)tls + tid*16);
      st_b128_ic(slot + tid*8, v);
    } else {
      u32x2 v = *(const u32x2*)((const char*)tls + tid*8);
      st_b64_ic(slot + tid*4, v);
    }
    asm volatile("s_waitcnt vmcnt(0)" ::: "memory");
    __syncthreads();
    const int target = fbase + tl + 1;
    if (tid == 0)
      __hip_atomic_store(myflag, target, __ATOMIC_RELAXED, __HIP_MEMORY_SCOPE_AGENT);

    if (wave == 7 && lane < 3){
      const int* pf = flags + (g*4 + ((c + 1 + lane) & 3))*32;
      while (__hip_atomic_load(pf, __ATOMIC_RELAXED, __HIP_MEMORY_SCOPE_AGENT) < target)
        __builtin_amdgcn_s_sleep(1);
    }
    __syncthreads();

    const unsigned short* mbb = mb + (size_t)((g*2 + (tl & 1))*4)*4096;
    const unsigned short* s0 = mbb;
    const unsigned short* s1 = mbb + 4096;
    const unsigned short* s2 = mbb + 8192;
    const unsigned short* s3 = mbb + 12288;
    u32x2 q0,q1,q2,q3,q4,q5;
    LD2_IC(q0, s0 + rrow*256 + rc0);
    LD2_IC(q1, s1 + rrow*256 + rc0);
    LD2_IC(q2, s0 + rrow*256 + 128 + rc0);
    LD2_IC(q3, s1 + rrow*256 + 128 + rc0);
    LD2_IC(q4, s2 + rrow*128 + rc0);
    LD2_IC(q5, s3 + rrow*128 + rc0);
    asm volatile("s_waitcnt vmcnt(0)" ::: "memory");
    __builtin_amdgcn_sched_barrier(0);

    f32x4 mup = cvt4(q0) + cvt4(q1);
    f32x4 lsv = cvt4(q2) + cvt4(q3) + bl4;
    f32x4 muq = cvt4(q4) + cvt4(q5);
    f32x4 muv = (muq + bq4) + (mup + bp4);
    f32x4 zv;
    #pragma unroll
    for (int i=0; i<4; i++) zv[i] = muv[i] + __expf(0.5f * lsv[i]) * er[i];

    unsigned int lo = (unsigned)f2bf(zv[0]) | ((unsigned)f2bf(zv[1]) << 16);
    unsigned int hi = (unsigned)f2bf(zv[2]) | ((unsigned)f2bf(zv[3]) << 16);
    uint2 zp; zp.x = lo; zp.y = hi;
    *(uint2*)((char*)zls + swz256(rrow*256 + rc0*2)) = zp;
    if (c == 0){
      *(f32x4*)(out_mu + growr*STATE + rc0) = muv;
      *(f32x4*)(out_ls + growr*STATE + rc0) = lsv;
      if (t0 + tl == LSEQ-1)
        *(f32x4*)(out_zn + ((size_t)(brow0 + rrow))*STATE + rc0) = zv;
    }
    __syncthreads();

    #pragma unroll
    for (int nt=0; nt<2; nt++)
      #pragma unroll
      for (int r=0; r<4; r++){ pa0[nt][r] = pa1[nt][r]; pb0[nt][r] = pb1[nt][r]; }
  }

  if (c == 0){
    unsigned short* zso = z_state + (size_t)brow0 * 128;
    for (int i = tid; i < 16*128; i += 512){
      int row = i >> 7, col = i & 127;
      zso[row*128 + col] = *(const unsigned short*)((const char*)zls + swz256(row*256 + col*2));
    }
  }
}

// ---------------- host launcher ----------------
extern "C" void kernel_launch(void* const* d_in, const int* in_sizes, int n_in,
                              void* d_out, int out_size, void* d_ws, size_t ws_size,
                              hipStream_t stream)
{
  const float* ext = (const float*)d_in[0];
  const float* obs = (const float*)d_in[1];
  const float* eps = (const float*)d_in[2];
  const float* Wu  = (const float*)d_in[3];
  const float* bu  = (const float*)d_in[4];
  const float* Wx  = (const float*)d_in[5];
  const float* bx  = (const float*)d_in[6];
  const float* W_ih= (const float*)d_in[7];
  const float* b_ih= (const float*)d_in[8];
  const float* W_hh= (const float*)d_in[9];
  const float* b_hh= (const float*)d_in[10];
  const float* Wa1 = (const float*)d_in[11];
  const float* ba1 = (const float*)d_in[12];
  const float* Wa2 = (const float*)d_in[13];
  const float* ba2 = (const float*)d_in[14];
  const float* pf1W= (const float*)d_in[15]; const float* pf1b = (const float*)d_in[16];
  const float* pf2W= (const float*)d_in[17]; const float* pf2b = (const float*)d_in[18];
  const float* pmuW= (const float*)d_in[19]; const float* pmub = (const float*)d_in[20];
  const float* plsW= (const float*)d_in[21]; const float* plsb = (const float*)d_in[22];
  const float* qf1W= (const float*)d_in[23]; const float* qf1b = (const float*)d_in[24];
  const float* qf2W= (const float*)d_in[25]; const float* qf2b = (const float*)d_in[26];
  const float* qmuW= (const float*)d_in[27]; const float* qmub = (const float*)d_in[28];

  int NC = 0;
  const int cands[7] = {1,2,4,8,16,32,64};
  size_t rows = 0;
  for (int ci=0; ci<7; ci++){
    size_t r = (size_t)(LSEQ/cands[ci])*BATCH;
    size_t elems = 3400000 + r*3072;
    if (elems * 2 <= ws_size){ NC = cands[ci]; rows = r; break; }
  }
  if (!NC) return;
  const int nsteps = LSEQ/NC;
  const int gx = (int)(rows/128);

  unsigned short* ws = (unsigned short*)d_ws;
  size_t off = 0;
  auto alloc = [&](size_t elems){
    unsigned short* p = ws + off;
    off += (elems + 127) & ~(size_t)127;
    return p;
  };

  unsigned short* Wu_t  = alloc(64*256);
  unsigned short* Wx_t  = alloc(64*256);
  unsigned short* Wih_t = alloc(256*256);
  unsigned short* Whh_t = alloc(256*256);
  unsigned short* Wa1_t = alloc(512*256);
  unsigned short* Wa2_t = alloc(256*256);
  unsigned short* fAp   = alloc(1024*256);     // [f1(512) | f2(512)] x [256 k]
  unsigned short* fAq   = alloc(1024*256);
  unsigned short* Wzz   = alloc(4*2*256*128);  // [role][mat][n][k]
  unsigned short* W2z   = alloc(4*2*128*256);  // [role][mat][n][k]
  unsigned short* d_state = alloc(256*256);
  unsigned short* z_state = alloc(256*128);
  unsigned short* mbx  = alloc(16*2*4*4096);   // bf16 mailbox
  int*   flg  = (int*)alloc(4096);             // 2048 ints
  unsigned short* bufA  = alloc(rows*256);
  unsigned short* bufB  = alloc(rows*256);
  unsigned short* bufC  = alloc(rows*512);
  unsigned short* preP  = alloc(rows*1024);
  unsigned short* preQ  = alloc(rows*1024);
  if (off * sizeof(unsigned short) > ws_size) return;

  float* out_mu = (float*)d_out;
  float* out_ls = out_mu + (size_t)LSEQ*BATCH*STATE;
  float* out_dn = out_ls + (size_t)LSEQ*BATCH*STATE;
  float* out_zn = out_dn + (size_t)BATCH*KDIM;

  WDescs wd;
  int wi = 0;
  auto add = [&](const float* s, unsigned short* d, int Kk, int Nn, int ld, int ro, int co){
    wd.d[wi].src = s; wd.d[wi].dst = d; wd.d[wi].K = Kk; wd.d[wi].N = Nn;
    wd.d[wi].ld = ld; wd.d[wi].rowoff = ro; wd.d[wi].coloff = co; wi++;
  };
  add(Wu,   Wu_t,  64, 256, 256, 0, 0);
  add(Wx,   Wx_t,  64, 256, 256, 0, 0);
  add(W_ih, Wih_t, 256, 256, 256, 0, 0);
  add(W_hh, Whh_t, 256, 256, 256, 0, 0);
  add(Wa1,  Wa1_t, 512, 256, 256, 0, 0);
  add(Wa2,  Wa2_t, 256, 256, 256, 0, 0);
  add(pf1W, fAp,            256, 512, 512, 128, 0);
  add(pf2W, fAp + 512*256,  256, 512, 512, 128, 0);
  add(qf1W, fAq,            256, 512, 512, 128, 0);
  add(qf2W, fAq + 512*256,  256, 512, 512, 128, 0);
  for (int c=0; c<4; c++){
    const float* s1 = (c < 2) ? pf1W : qf1W;
    const float* s2 = (c < 2) ? pf2W : qf2W;
    add(s1, Wzz + (size_t)(c*2+0)*32768, 128, 256, 512, 0, (c&1)*256);
    add(s2, Wzz + (size_t)(c*2+1)*32768, 128, 256, 512, 0, (c&1)*256);
  }
  add(pmuW, W2z + (size_t)(0*2+0)*32768, 256, 128, 128, 0,   0);
  add(plsW, W2z + (size_t)(0*2+1)*32768, 256, 128, 128, 0,   0);
  add(pmuW, W2z + (size_t)(1*2+0)*32768, 256, 128, 128, 256, 0);
  add(plsW, W2z + (size_t)(1*2+1)*32768, 256, 128, 128, 256, 0);
  add(qmuW, W2z + (size_t)(2*2+0)*32768, 256, 128, 128, 0,   0);
  add(qmuW, W2z + (size_t)(3*2+0)*32768, 256, 128, 128, 256, 0);

  convert_weights<<<dim3(512,24), 256, 0, stream>>>(wd);
  init_flags<<<8, 256, 0, stream>>>(flg);

  for (int c=0; c<NC; ++c){
    const int t0 = c * nsteps;
    const size_t row0 = (size_t)t0 * BATCH;

    GArgs e{};
    e.g[0] = GArg{ext + row0*64, Wu_t, bu, bu, bufA, 64, 256, 0,   64, 1, 1};
    e.g[1] = GArg{obs + row0*64, Wx_t, bx, bx, bufC, 64, 512, 256, 64, 1, 1};
    gemm_multi<<<dim3(gx,2,2), 256, 0, stream>>>(e);

    GArgs2 rn{};
    rn.g[0] = GArg2{bufA, Wih_t, b_ih, b_ih, bufB, 256, 256, 0, 256, 0};
    gemm_glds<<<dim3(gx,2,1), 256, 0, stream>>>(rn);

    rnn_chunk<<<16, 256, 0, stream>>>(bufB, Whh_t, b_hh, bufC, out_dn, d_state, t0, nsteps);

    GArgs2 a1{};
    a1.g[0] = GArg2{bufC, Wa1_t, ba1, ba1, bufA, 512, 256, 0, 512, 1};
    gemm_glds<<<dim3(gx,2,1), 256, 0, stream>>>(a1);

    GArgs2 a2{};
    a2.g[0] = GArg2{bufA, Wa2_t, ba2, ba2, bufB, 256, 256, 0, 256, 0};
    gemm_glds<<<dim3(gx,2,1), 256, 0, stream>>>(a2);

    GArgs2 pr{};
    pr.g[0] = GArg2{bufB, fAp, pf1b, pf2b, preP, 256, 1024, 0, 256, 0};
    pr.g[1] = GArg2{bufC, fAq, qf1b, qf2b, preQ, 512, 1024, 0, 256, 0};
    gemm_glds<<<dim3(gx,8,2), 256, 0, stream>>>(pr);

    zrec_mb<<<64, 512, 0, stream>>>(preP, preQ, Wzz, W2z,
                                    pmub, plsb, qmub, eps, out_mu, out_ls, out_zn,
                                    z_state, mbx, flg, t0, nsteps, c*nsteps);
  }
}